// Round 9
// baseline (791.147 us; speedup 1.0000x reference)
//
#include <hip/hip_runtime.h>
#include <hip/hip_bf16.h>
#include <math.h>

#define B 16
#define S 511
#define F 128
#define D 512
#define H 8
#define NB 6
#define DH 64
#define MLPD 2048
#define T 512
#define EPS 1e-5f

typedef unsigned short ushort;
typedef __attribute__((ext_vector_type(8))) short short8;
typedef __attribute__((ext_vector_type(4))) float floatx4;

__device__ __forceinline__ ushort f2bf(float f) {
    union { float f; unsigned u; } cv; cv.f = f;
    unsigned r = (cv.u + 0x7fff + ((cv.u >> 16) & 1)) >> 16;  // RNE
    return (ushort)r;
}

// Branch-free erf (Abramowitz-Stegun 7.1.26, |err| <= 1.5e-7)
__device__ __forceinline__ float fast_gelu(float x) {
    float z = fabsf(x) * 0.70710678118f;
    float t = 1.0f / (1.0f + 0.3275911f * z);
    float p = ((((1.061405429f * t - 1.453152027f) * t + 1.421413741f) * t
               - 0.284496736f) * t + 0.254829592f) * t;
    float erfv = 1.0f - p * __expf(-z * z);
    erfv = copysignf(erfv, x);
    return 0.5f * x * (1.0f + erfv);
}

// ---------------- cast src -> bf16 A-matrix for embed GEMM (t=0 rows zeroed) ----------------
__global__ void castsrc_kernel(const float* __restrict__ src, ushort* __restrict__ srcb) {
    int row = blockIdx.x;              // b*T + t
    int t = row & (T - 1), b = row >> 9;
    int tid = threadIdx.x;             // 128
    ushort v = 0;
    if (t > 0) v = f2bf(src[((size_t)b * S + (t - 1)) * F + tid]);
    srcb[(size_t)row * F + tid] = v;
}

// ---------------- generic transpose+cast: W [mat,K,N] fp32 -> Wt [mat,N,K] bf16 ----------------
__global__ void wtrans_kernel(const float* __restrict__ W,
                              ushort* __restrict__ Wt,
                              int K, int N) {
    int kb = blockIdx.x * 32, nb = blockIdx.y * 32, mat = blockIdx.z;
    __shared__ float tile[32][33];
    int tid = threadIdx.x; // 256
    int c = tid & 31, r0 = tid >> 5;
    const float* Wm = W + (size_t)mat * K * N;
    ushort* Wtm = Wt + (size_t)mat * K * N;
    #pragma unroll
    for (int l = 0; l < 4; ++l) {
        int r = r0 + l * 8;
        tile[r][c] = Wm[(size_t)(kb + r) * N + nb + c];
    }
    __syncthreads();
    #pragma unroll
    for (int l = 0; l < 4; ++l) {
        int r = r0 + l * 8;
        Wtm[(size_t)(nb + r) * K + kb + c] = f2bf(tile[c][r]);
    }
}

// ---------------- qkv weight transpose+cast ----------------
__global__ void wtransq_kernel(const float* __restrict__ Wq, const float* __restrict__ Wk,
                               const float* __restrict__ Wv,
                               ushort* __restrict__ WqT, ushort* __restrict__ WkT,
                               ushort* __restrict__ WvT) {
    int mat = blockIdx.x;          // 0..NB*H-1
    int which = blockIdx.y;        // 0,1,2
    const float* W = (which == 0 ? Wq : which == 1 ? Wk : Wv) + (size_t)mat * 4096;
    ushort* O = (which == 0 ? WqT : which == 1 ? WkT : WvT) + (size_t)mat * 4096;
    __shared__ float t[64][65];
    int tid = threadIdx.x;  // 256
    int r0 = tid >> 6, c = tid & 63;
    #pragma unroll
    for (int l = 0; l < 16; ++l) {
        int row = r0 * 16 + l;
        t[row][c] = W[row * 64 + c];
    }
    __syncthreads();
    #pragma unroll
    for (int l = 0; l < 16; ++l) {
        int row = r0 * 16 + l;
        O[row * 64 + c] = f2bf(t[c][row]);
    }
}

// ---------------- async global->LDS helper ----------------
__device__ __forceinline__ void gload_lds16(const ushort* g, ushort* l) {
    __builtin_amdgcn_global_load_lds((const __attribute__((address_space(1))) unsigned int*)g,
                                     (__attribute__((address_space(3))) unsigned int*)l,
                                     16, 0, 0);
}

#define S_WAITCNT_VM(N) asm volatile("s_waitcnt vmcnt(" #N ")" ::: "memory")
#define S_WAITCNT_LGKM0 asm volatile("s_waitcnt lgkmcnt(0)" ::: "memory")
#define S_WAITCNT_LGKM8 asm volatile("s_waitcnt lgkmcnt(8)" ::: "memory")

// ---------------- embed GEMM: x = concat(cls, srcb@embWt^T)+emb_b+pe, fp32 out ----------------
__global__ __launch_bounds__(256) void embed_gemm(const ushort* __restrict__ A,
                                                  const ushort* __restrict__ Bt,
                                                  const float* __restrict__ emb_b,
                                                  const float* __restrict__ cls_tok,
                                                  float* __restrict__ x) {
    __shared__ ushort As[64 * 32];
    __shared__ ushort Bs[64 * 32];
    int tid = threadIdx.x;
    int lane = tid & 63;
    int w = __builtin_amdgcn_readfirstlane(tid >> 6);
    int quad = lane >> 4, l15 = lane & 15;
    int wr = (w >> 1) * 32, wc = (w & 1) * 32;
    int m0 = blockIdx.x * 64, n0 = blockIdx.y * 64;

    floatx4 acc[2][2];
    #pragma unroll
    for (int i = 0; i < 2; ++i)
        #pragma unroll
        for (int j = 0; j < 2; ++j) acc[i][j] = (floatx4)0.f;

    int lrow = lane >> 2;
    int lk = (lane & 3) * 8;
    const ushort* Ag = A + (size_t)(m0 + 16 * w + lrow) * F + lk;
    const ushort* Bg = Bt + (size_t)(n0 + 16 * w + lrow) * F + lk;
    ushort* AsW = &As[16 * w * 32];
    ushort* BsW = &Bs[16 * w * 32];
    int fa = l15 * 32 + quad * 8;

    for (int kt = 0; kt < F; kt += 32) {
        gload_lds16(Ag + kt, AsW);
        gload_lds16(Bg + kt, BsW);
        __syncthreads();
        short8 af[2], bf[2];
        #pragma unroll
        for (int i = 0; i < 2; ++i) af[i] = *(const short8*)&As[(wr + 16 * i) * 32 + fa];
        #pragma unroll
        for (int j = 0; j < 2; ++j) bf[j] = *(const short8*)&Bs[(wc + 16 * j) * 32 + fa];
        #pragma unroll
        for (int i = 0; i < 2; ++i)
            #pragma unroll
            for (int j = 0; j < 2; ++j)
                acc[i][j] = __builtin_amdgcn_mfma_f32_16x16x32_bf16(af[i], bf[j], acc[i][j], 0, 0, 0);
        __syncthreads();
    }

    const float LOG1E4 = 9.210340371976184f;
    int rbase = (lane >> 4) * 4;
    int cidx = lane & 15;
    #pragma unroll
    for (int j = 0; j < 2; ++j) {
        int gc = n0 + wc + 16 * j + cidx;
        float je = (float)(gc & ~1);
        float freq = expf(-(je / (float)D) * LOG1E4);
        float ebv = emb_b[gc];
        float clsv = cls_tok[gc];
        bool odd = (gc & 1);
        #pragma unroll
        for (int i = 0; i < 2; ++i) {
            int gr = m0 + wr + 16 * i + rbase;
            #pragma unroll
            for (int reg = 0; reg < 4; ++reg) {
                int row = gr + reg;
                int t = row & (T - 1);
                float ang = (float)t * freq;
                float pe = odd ? cosf(ang) : sinf(ang);
                float val = (t == 0) ? (clsv + pe) : (acc[i][j][reg] + ebv + pe);
                x[(size_t)row * D + gc] = val;
            }
        }
    }
}

// ---------------- layernorm -> bf16: one wave per row, shuffle-only ----------------
__global__ __launch_bounds__(256) void ln_kernel(const float* __restrict__ xin,
                                                 const float* __restrict__ g,
                                                 const float* __restrict__ bb,
                                                 ushort* __restrict__ out) {
    int lane = threadIdx.x & 63;
    int row = blockIdx.x * 4 + (threadIdx.x >> 6);
    const float* xr = xin + (size_t)row * D + lane * 8;
    float4 a0 = *(const float4*)xr;
    float4 a1 = *(const float4*)(xr + 4);
    float s = a0.x + a0.y + a0.z + a0.w + a1.x + a1.y + a1.z + a1.w;
    #pragma unroll
    for (int off = 1; off < 64; off <<= 1) s += __shfl_xor(s, off);
    float mean = s * (1.0f / (float)D);
    float d0 = a0.x - mean, d1 = a0.y - mean, d2 = a0.z - mean, d3 = a0.w - mean;
    float d4 = a1.x - mean, d5 = a1.y - mean, d6 = a1.z - mean, d7 = a1.w - mean;
    float sq = d0*d0 + d1*d1 + d2*d2 + d3*d3 + d4*d4 + d5*d5 + d6*d6 + d7*d7;
    #pragma unroll
    for (int off = 1; off < 64; off <<= 1) sq += __shfl_xor(sq, off);
    float rstd = rsqrtf(sq * (1.0f / (float)D) + EPS);
    const float* gp = g + lane * 8;
    const float* bp = bb + lane * 8;
    float4 g0 = *(const float4*)gp, g1 = *(const float4*)(gp + 4);
    float4 b0 = *(const float4*)bp, b1 = *(const float4*)(bp + 4);
    short8 o;
    o[0] = (short)f2bf(d0 * rstd * g0.x + b0.x);
    o[1] = (short)f2bf(d1 * rstd * g0.y + b0.y);
    o[2] = (short)f2bf(d2 * rstd * g0.z + b0.z);
    o[3] = (short)f2bf(d3 * rstd * g0.w + b0.w);
    o[4] = (short)f2bf(d4 * rstd * g1.x + b1.x);
    o[5] = (short)f2bf(d5 * rstd * g1.y + b1.y);
    o[6] = (short)f2bf(d6 * rstd * g1.z + b1.z);
    o[7] = (short)f2bf(d7 * rstd * g1.w + b1.w);
    *(short8*)(out + (size_t)row * D + lane * 8) = o;
}

// ---------------- fused LN1 + QKV: 32-row block; LN into padded LDS, then per-head MFMA ------
#define LQPAD 520
__global__ __launch_bounds__(256) void lnqkv_kernel(
        const float* __restrict__ x,
        const float* __restrict__ g, const float* __restrict__ bb,
        const ushort* __restrict__ WqT, const float* __restrict__ bq,
        const ushort* __restrict__ WkT, const float* __restrict__ bk,
        const ushort* __restrict__ WvT, const float* __restrict__ bv,
        ushort* __restrict__ qo, ushort* __restrict__ ko, ushort* __restrict__ vTo) {
    __shared__ ushort hl[32 * LQPAD];   // 33.3 KB
    int tid = threadIdx.x;
    int lane = tid & 63;
    int w = __builtin_amdgcn_readfirstlane(tid >> 6);   // 0..3
    int quad = lane >> 4, l15 = lane & 15;
    int m0 = blockIdx.x * 32;

    for (int it = 0; it < 8; ++it) {
        int lr = it * 4 + w;
        const float* xr = x + (size_t)(m0 + lr) * D + lane * 8;
        float4 a0 = *(const float4*)xr;
        float4 a1 = *(const float4*)(xr + 4);
        float s = a0.x + a0.y + a0.z + a0.w + a1.x + a1.y + a1.z + a1.w;
        #pragma unroll
        for (int off = 1; off < 64; off <<= 1) s += __shfl_xor(s, off);
        float mean = s * (1.0f / (float)D);
        float d0 = a0.x - mean, d1 = a0.y - mean, d2 = a0.z - mean, d3 = a0.w - mean;
        float d4 = a1.x - mean, d5 = a1.y - mean, d6 = a1.z - mean, d7 = a1.w - mean;
        float sq = d0*d0 + d1*d1 + d2*d2 + d3*d3 + d4*d4 + d5*d5 + d6*d6 + d7*d7;
        #pragma unroll
        for (int off = 1; off < 64; off <<= 1) sq += __shfl_xor(sq, off);
        float rstd = rsqrtf(sq * (1.0f / (float)D) + EPS);
        const float* gp = g + lane * 8;
        const float* bp = bb + lane * 8;
        float4 g0 = *(const float4*)gp, g1 = *(const float4*)(gp + 4);
        float4 b0 = *(const float4*)bp, b1v = *(const float4*)(bp + 4);
        short8 o;
        o[0] = (short)f2bf(d0 * rstd * g0.x + b0.x);
        o[1] = (short)f2bf(d1 * rstd * g0.y + b0.y);
        o[2] = (short)f2bf(d2 * rstd * g0.z + b0.z);
        o[3] = (short)f2bf(d3 * rstd * g0.w + b0.w);
        o[4] = (short)f2bf(d4 * rstd * g1.x + b1v.x);
        o[5] = (short)f2bf(d5 * rstd * g1.y + b1v.y);
        o[6] = (short)f2bf(d6 * rstd * g1.z + b1v.z);
        o[7] = (short)f2bf(d7 * rstd * g1.w + b1v.w);
        *(short8*)(hl + lr * LQPAD + lane * 8) = o;
    }
    __syncthreads();

    int bb_ = m0 >> 9;
    #pragma unroll
    for (int hp = 0; hp < 2; ++hp) {
        int hh = w * 2 + hp;
        short8 af[2][2];
        #pragma unroll
        for (int mt = 0; mt < 2; ++mt)
            #pragma unroll
            for (int ks = 0; ks < 2; ++ks)
                af[mt][ks] = *(const short8*)&hl[(mt * 16 + l15) * LQPAD + hh * DH + ks * 32 + quad * 8];

        floatx4 acc[3][2][4];
        #pragma unroll
        for (int xo = 0; xo < 3; ++xo)
            #pragma unroll
            for (int mt = 0; mt < 2; ++mt)
                #pragma unroll
                for (int nt = 0; nt < 4; ++nt) acc[xo][mt][nt] = (floatx4)0.f;

        #pragma unroll
        for (int xo = 0; xo < 3; ++xo) {
            const ushort* WT = (xo == 0 ? WqT : xo == 1 ? WkT : WvT) + (size_t)hh * 4096;
            #pragma unroll
            for (int nt = 0; nt < 4; ++nt) {
                const ushort* wb = WT + (size_t)(nt * 16 + l15) * 64 + quad * 8;
                short8 bf0 = *(const short8*)(wb);
                short8 bf1 = *(const short8*)(wb + 32);
                #pragma unroll
                for (int mt = 0; mt < 2; ++mt) {
                    acc[xo][mt][nt] = __builtin_amdgcn_mfma_f32_16x16x32_bf16(af[mt][0], bf0, acc[xo][mt][nt], 0, 0, 0);
                    acc[xo][mt][nt] = __builtin_amdgcn_mfma_f32_16x16x32_bf16(af[mt][1], bf1, acc[xo][mt][nt], 0, 0, 0);
                }
            }
        }

        int bh = bb_ * H + hh;
        #pragma unroll
        for (int mt = 0; mt < 2; ++mt) {
            int trow = m0 + mt * 16 + quad * 4;
            int tt = trow & (T - 1);
            #pragma unroll
            for (int nt = 0; nt < 4; ++nt) {
                int col = nt * 16 + l15;
                float bqv = bq[hh * DH + col];
                float bkv = bk[hh * DH + col];
                float bvv = bv[hh * DH + col];
                #pragma unroll
                for (int reg = 0; reg < 4; ++reg) {
                    qo[((size_t)bh * T + tt + reg) * DH + col] = f2bf(acc[0][mt][nt][reg] + bqv);
                    ko[((size_t)bh * T + tt + reg) * DH + col] = f2bf(acc[1][mt][nt][reg] + bkv);
                    vTo[((size_t)bh * DH + col) * T + tt + reg] = f2bf(acc[2][mt][nt][reg] + bvv);
                }
            }
        }
    }
}

// ---------------- MFMA flash attention, max-free softmax + deferred normalization ------------
// grid (qt, bh): the 8 qt-blocks sharing a head's K/V are launch-adjacent (L2 window).
// Softmax P->bf16 via v_cvt_pk_bf16_f32 pairs (RNE, same as f2bf): ~45 VALU ops/lane/iter saved.
#define PSTRIDE 88
__global__ __launch_bounds__(256) void attn_kernel(const ushort* __restrict__ q,
                                                   const ushort* __restrict__ k,
                                                   const ushort* __restrict__ vT,
                                                   float* __restrict__ x) {
    int bh = blockIdx.y;
    int qt = blockIdx.x;
    int b = bh >> 3, hh = bh & 7;
    int tid = threadIdx.x;
    int lane = tid & 63;
    int w = __builtin_amdgcn_readfirstlane(tid >> 6);   // 0..3
    int quad = lane >> 4, l15 = lane & 15;

    __shared__ __align__(16) ushort smem[22016];   // 44032 B
    ushort* Pw = smem + 16384 + w * (16 * PSTRIDE);

    const ushort* qbase = q + ((size_t)bh * T + qt * 64 + w * 16 + l15) * DH + quad * 8;
    short8 Qf0 = *(const short8*)(qbase);
    short8 Qf1 = *(const short8*)(qbase + 32);

    const ushort* kbase = k + (size_t)bh * T * DH;
    const ushort* vbase = vT + (size_t)bh * DH * T;

    int srow = lane >> 2;
    int scol = (lane & 3) * 8;
    const ushort* kg = kbase + (size_t)(w * 16 + srow) * DH + scol;
    const ushort* vg = vbase + (size_t)(w * 16 + srow) * T + scol;
    ushort* ldsK = smem + w * 16 * 32;
    ushort* ldsV = smem + 8192 + w * 16 * 32;

    float l_i[4] = {0.f, 0.f, 0.f, 0.f};
    floatx4 O[4];
    #pragma unroll
    for (int j = 0; j < 4; ++j) O[j] = (floatx4)0.f;

    gload_lds16(kg, ldsK);
    gload_lds16(kg + 32, ldsK + 2048);
    gload_lds16(vg, ldsV);
    gload_lds16(vg + 32, ldsV + 2048);
    __syncthreads();

    for (int kt = 0; kt < T / 64; ++kt) {
        int cur = kt & 1;
        if (kt < T / 64 - 1) {
            int nb = cur ^ 1;
            const ushort* kgn = kg + (size_t)(kt + 1) * 64 * DH;
            const ushort* vgn = vg + (kt + 1) * 64;
            gload_lds16(kgn, ldsK + nb * 4096);
            gload_lds16(kgn + 32, ldsK + nb * 4096 + 2048);
            gload_lds16(vgn, ldsV + nb * 4096);
            gload_lds16(vgn + 32, ldsV + nb * 4096 + 2048);
        }
        const ushort* Kc = smem + cur * 4096;
        const ushort* Vc = smem + 8192 + cur * 4096;

        floatx4 sc[4];
        __builtin_amdgcn_s_setprio(1);
        #pragma unroll
        for (int j = 0; j < 4; ++j) {
            int ro = (j * 16 + l15) * 32 + quad * 8;
            short8 kf0 = *(const short8*)&Kc[ro];
            short8 kf1 = *(const short8*)&Kc[2048 + ro];
            floatx4 s4 = (floatx4)0.f;
            s4 = __builtin_amdgcn_mfma_f32_16x16x32_bf16(Qf0, kf0, s4, 0, 0, 0);
            s4 = __builtin_amdgcn_mfma_f32_16x16x32_bf16(Qf1, kf1, s4, 0, 0, 0);
            sc[j] = s4;
        }
        __builtin_amdgcn_s_setprio(0);
        #pragma unroll
        for (int j = 0; j < 4; ++j) {
            float p0 = __expf(sc[j][0] * 0.125f);
            float p1 = __expf(sc[j][1] * 0.125f);
            float p2 = __expf(sc[j][2] * 0.125f);
            float p3 = __expf(sc[j][3] * 0.125f);
            l_i[0] += p0; l_i[1] += p1; l_i[2] += p2; l_i[3] += p3;
            unsigned pk01, pk23;
            asm("v_cvt_pk_bf16_f32 %0, %1, %2" : "=v"(pk01) : "v"(p0), "v"(p1));
            asm("v_cvt_pk_bf16_f32 %0, %1, %2" : "=v"(pk23) : "v"(p2), "v"(p3));
            ushort* pb = &Pw[(quad * 4) * PSTRIDE + j * 16 + l15];
            pb[0] = (ushort)pk01;
            pb[PSTRIDE] = (ushort)(pk01 >> 16);
            pb[2 * PSTRIDE] = (ushort)pk23;
            pb[3 * PSTRIDE] = (ushort)(pk23 >> 16);
        }

        short8 af0 = *(const short8*)&Pw[l15 * PSTRIDE + quad * 8];
        short8 af1 = *(const short8*)&Pw[l15 * PSTRIDE + 32 + quad * 8];
        __builtin_amdgcn_s_setprio(1);
        #pragma unroll
        for (int j = 0; j < 4; ++j) {
            int ro = (j * 16 + l15) * 32 + quad * 8;
            short8 vf0 = *(const short8*)&Vc[ro];
            short8 vf1 = *(const short8*)&Vc[2048 + ro];
            O[j] = __builtin_amdgcn_mfma_f32_16x16x32_bf16(af0, vf0, O[j], 0, 0, 0);
            O[j] = __builtin_amdgcn_mfma_f32_16x16x32_bf16(af1, vf1, O[j], 0, 0, 0);
        }
        __builtin_amdgcn_s_setprio(0);
        __syncthreads();
    }

    #pragma unroll
    for (int r = 0; r < 4; ++r) {
        l_i[r] += __shfl_xor(l_i[r], 1);
        l_i[r] += __shfl_xor(l_i[r], 2);
        l_i[r] += __shfl_xor(l_i[r], 4);
        l_i[r] += __shfl_xor(l_i[r], 8);
    }

    float* Ow = (float*)smem + w * 16 * 68;
    #pragma unroll
    for (int r = 0; r < 4; ++r) {
        float rl = 1.0f / l_i[r];
        #pragma unroll
        for (int j = 0; j < 4; ++j)
            Ow[(quad * 4 + r) * 68 + j * 16 + l15] = O[j][r] * rl;
    }
    __syncthreads();
    int r4 = lane >> 4;
    int c16 = lane & 15;
    #pragma unroll
    for (int i = 0; i < 4; ++i) {
        int lrow = i * 4 + r4;
        float4 o = *(const float4*)&Ow[lrow * 68 + c16 * 4];
        int grow = qt * 64 + w * 16 + lrow;
        float* xp = &x[((size_t)(b * T) + grow) * D + hh * DH + c16 * 4];
        float4 xv = *(const float4*)xp;
        xv.x += o.x; xv.y += o.y; xv.z += o.z; xv.w += o.w;
        *(float4*)xp = xv;
    }
}

// ---------------- gemm1: m201-style 256x256 8-phase, BK=64, 2 K-tiles/iter, counted vmcnt ----
// (r8-verified; ledger in r8 commit message)
__global__ __launch_bounds__(512, 1) void gemm1_8p(const ushort* __restrict__ A,
                                                   const ushort* __restrict__ Bt,
                                                   const float* __restrict__ bias,
                                                   ushort* __restrict__ C,
                                                   int N, int K) {
    constexpr int BUF = 32768;
    constexpr int BOFS = 16384;
    __shared__ ushort lds[2 * BUF];

    int tid = threadIdx.x;
    int lane = tid & 63;
    int w = __builtin_amdgcn_readfirstlane(tid >> 6);
    int quad = lane >> 4, l15 = lane & 15;
    int wm = w >> 2, wn = w & 3;
    int wmr = wm * 128, wnr = wn * 64;

    int nwg = gridDim.x;
    int id = blockIdx.x;
    int idx = (id & 7) * (nwg >> 3) + (id >> 3);
    int NTg = N >> 8;
    int mt = idx / NTg, nt = idx - mt * NTg;
    int m0 = mt * 256, n0 = nt * 256;

    int strow = tid >> 3;
    int ssw = ((tid & 7) ^ (strow & 7)) * 8;
    const ushort* Ag = A + (size_t)(m0 + strow) * K + ssw;
    const ushort* Bg = Bt + (size_t)(n0 + strow) * K + ssw;
    int wdst = w << 9;

    int sx0 = (quad ^ (l15 & 7)) * 8;
    int sx1 = ((4 + quad) ^ (l15 & 7)) * 8;

    floatx4 acc[8][4];
    #pragma unroll
    for (int i = 0; i < 8; ++i)
        #pragma unroll
        for (int n = 0; n < 4; ++n) acc[i][n] = (floatx4)0.f;

    short8 a[4][2], b[4][2];

    #define STG_AH(h, t, bp) do {                                                         \
        gload_lds16(Ag + (size_t)((h) * 128) * K + (size_t)(t) * 64,                      \
                    (bp) + ((h) * 128) * 64 + wdst);                                      \
        gload_lds16(Ag + (size_t)((h) * 128 + 64) * K + (size_t)(t) * 64,                 \
                    (bp) + ((h) * 128 + 64) * 64 + wdst);                                 \
    } while (0)
    #define STG_BH(h, t, bp) do {                                                         \
        gload_lds16(Bg + (size_t)((h) * 128) * K + (size_t)(t) * 64,                      \
                    (bp) + BOFS + ((h) * 128) * 64 + wdst);                                \
        gload_lds16(Bg + (size_t)((h) * 128 + 64) * K + (size_t)(t) * 64,                 \
                    (bp) + BOFS + ((h) * 128 + 64) * 64 + wdst);                           \
    } while (0)

    #define RD_A03(bp) do { _Pragma("unroll")                                             \
        for (int ks = 0; ks < 2; ++ks) { int sx = ks ? sx1 : sx0;                         \
            _Pragma("unroll")                                                             \
            for (int i = 0; i < 4; ++i)                                                   \
                a[i][ks] = *(const short8*)&(bp)[(wmr + i * 16 + l15) * 64 + sx]; } } while (0)
    #define RD_A47(bp) do { _Pragma("unroll")                                             \
        for (int ks = 0; ks < 2; ++ks) { int sx = ks ? sx1 : sx0;                         \
            _Pragma("unroll")                                                             \
            for (int i = 0; i < 4; ++i)                                                   \
                a[i][ks] = *(const short8*)&(bp)[(wmr + (4 + i) * 16 + l15) * 64 + sx]; } } while (0)
    #define RD_B01(bp) do { _Pragma("unroll")                                             \
        for (int ks = 0; ks < 2; ++ks) { int sx = ks ? sx1 : sx0;                         \
            _Pragma("unroll")                                                             \
            for (int n = 0; n < 2; ++n)                                                   \
                b[n][ks] = *(const short8*)&(bp)[BOFS + (wnr + n * 16 + l15) * 64 + sx]; } } while (0)
    #define RD_B23(bp) do { _Pragma("unroll")                                             \
        for (int ks = 0; ks < 2; ++ks) { int sx = ks ? sx1 : sx0;                         \
            _Pragma("unroll")                                                             \
            for (int n = 0; n < 2; ++n)                                                   \
                b[2 + n][ks] = *(const short8*)&(bp)[BOFS + (wnr + (2 + n) * 16 + l15) * 64 + sx]; } } while (0)

    #define MFQ(mb, nb2) do { _Pragma("unroll")                                           \
        for (int ks = 0; ks < 2; ++ks)                                                    \
            _Pragma("unroll")                                                             \
            for (int i = 0; i < 4; ++i)                                                   \
                _Pragma("unroll")                                                         \
                for (int n = 0; n < 2; ++n)                                               \
                    acc[(mb) + i][(nb2) + n] = __builtin_amdgcn_mfma_f32_16x16x32_bf16(   \
                        a[i][ks], b[(nb2) + n][ks], acc[(mb) + i][(nb2) + n], 0, 0, 0); } while (0)

    #define BAR __builtin_amdgcn_s_barrier()
    #define PRIO_MFQ(mb, nb2) do { __builtin_amdgcn_s_setprio(1); MFQ(mb, nb2);           \
                                   __builtin_amdgcn_s_setprio(0); } while (0)

    ushort* buf0 = lds;
    ushort* buf1 = lds + BUF;

    STG_AH(0, 0, buf0); STG_AH(1, 0, buf0); STG_BH(0, 0, buf0); STG_BH(1, 0, buf0);
    STG_BH(0, 1, buf1); STG_BH(1, 1, buf1); STG_AH(0, 1, buf1);
    S_WAITCNT_VM(6);
    BAR;

    int NITER = K >> 7;
    int NT = K >> 6;
    for (int it = 0; it < NITER; ++it) {
        int t2 = 2 * it + 2, t3 = 2 * it + 3;
        bool s2 = (t2 < NT);
        RD_A03(buf0); RD_B01(buf0);
        STG_AH(1, 2 * it + 1, buf1);
        S_WAITCNT_LGKM8;
        BAR; S_WAITCNT_LGKM0; PRIO_MFQ(0, 0); BAR;
        RD_B23(buf0);
        BAR; S_WAITCNT_LGKM0; PRIO_MFQ(0, 2); BAR;
        RD_A47(buf0);
        if (s2) { STG_BH(0, t2, buf0); STG_BH(1, t2, buf0); }
        BAR; S_WAITCNT_LGKM0; PRIO_MFQ(4, 2); BAR;
        if (s2) { STG_AH(0, t2, buf0); S_WAITCNT_VM(6); } else { S_WAITCNT_VM(0); }
        BAR; PRIO_MFQ(4, 0); BAR;
        RD_A03(buf1); RD_B01(buf1);
        if (s2) STG_AH(1, t2, buf0);
        S_WAITCNT_LGKM8;
        BAR; S_WAITCNT_LGKM0; PRIO_MFQ(0, 0); BAR;
        RD_B23(buf1);
        BAR; S_WAITCNT_LGKM0; PRIO_MFQ(0, 2); BAR;
        RD_A47(buf1);
        if (s2) { STG_BH(0, t3, buf1); STG_BH(1, t3, buf1); }
        BAR; S_WAITCNT_LGKM0; PRIO_MFQ(4, 2); BAR;
        if (s2) { STG_AH(0, t3, buf1); S_WAITCNT_VM(6); }
        BAR; PRIO_MFQ(4, 0); BAR;
    }

    #undef STG_AH
    #undef STG_BH
    #undef RD_A03
    #undef RD_A47
    #undef RD_B01
    #undef RD_B23
    #undef MFQ
    #undef BAR
    #undef PRIO_MFQ

    int rbase = quad * 4;
    #pragma unroll
    for (int i = 0; i < 8; ++i) {
        #pragma unroll
        for (int n = 0; n < 4; ++n) {
            int gc = n0 + wnr + n * 16 + l15;
            float bv = bias[gc];
            int gr = m0 + wmr + i * 16 + rbase;
            #pragma unroll
            for (int reg = 0; reg < 4; ++reg) {
                C[(size_t)(gr + reg) * N + gc] = f2bf(fast_gelu(acc[i][n][reg] + bv));
            }
        }
    }
}

// ---------------- pipelined MFMA GEMM (gemm2, r1 bench-best): 3-buffer LDS, distance 2 ------
// EPI 2: C(fp32) += acc+bias (fused residual add).
template<int BM, int EPI>
__global__ __launch_bounds__(512) void gemm_pipe(const ushort* __restrict__ A,
                                                 const ushort* __restrict__ Bt,
                                                 const float* __restrict__ bias,
                                                 void* __restrict__ Cout,
                                                 int N, int K) {
    constexpr int BN = 128;
    constexpr int BK = 64;
    constexpr int MREP = BM / 32;
    constexpr int AJ = BM / 64;
    constexpr int TILE = (BM + BN) * BK;
    __shared__ ushort lds[3 * TILE];

    int tid = threadIdx.x;
    int lane = tid & 63;
    int w = __builtin_amdgcn_readfirstlane(tid >> 6);
    int quad = lane >> 4, l15 = lane & 15;
    int wrow = (w >> 2) * (BM / 2);
    int wcol = (w & 3) * 32;
    int m0 = blockIdx.x * BM, n0 = blockIdx.y * BN;

    int lrow8 = lane >> 3;
    int lslot = lane & 7;
    int scol = (lslot ^ lrow8) * 8;
    const ushort* Asrc = A + (size_t)(m0 + w * 8 + lrow8) * K + scol;
    const ushort* Bsrc = Bt + (size_t)(n0 + w * 8 + lrow8) * K + scol;
    ushort* ldsA0 = lds + (w * 8) * BK;
    ushort* ldsB0 = lds + BM * BK + (w * 8) * BK;

    int sx0 = ((quad) ^ (l15 & 7)) * 8;
    int sx1 = ((4 + quad) ^ (l15 & 7)) * 8;

    floatx4 acc[MREP][2];
    #pragma unroll
    for (int i = 0; i < MREP; ++i) {
        acc[i][0] = (floatx4)0.f;
        acc[i][1] = (floatx4)0.f;
    }

    #define STAGE_T(t, buf) do {                                                   \
        const ushort* ap_ = Asrc + (size_t)(t) * BK;                               \
        const ushort* bp_ = Bsrc + (size_t)(t) * BK;                               \
        ushort* la_ = ldsA0 + (buf) * TILE;                                        \
        ushort* lb_ = ldsB0 + (buf) * TILE;                                        \
        _Pragma("unroll")                                                          \
        for (int j = 0; j < AJ; ++j)                                               \
            gload_lds16(ap_ + (size_t)j * 64 * K, la_ + j * 64 * BK);              \
        _Pragma("unroll")                                                          \
        for (int j = 0; j < 2; ++j)                                                \
            gload_lds16(bp_ + (size_t)j * 64 * K, lb_ + j * 64 * BK);              \
    } while (0)

    #define COMPUTE_T(buf) do {                                                    \
        const ushort* Ab_ = lds + (buf) * TILE;                                    \
        const ushort* Bb_ = Ab_ + BM * BK;                                         \
        _Pragma("unroll")                                                          \
        for (int ks = 0; ks < 2; ++ks) {                                           \
            int sx_ = ks ? sx1 : sx0;                                              \
            short8 bfr0 = *(const short8*)&Bb_[(wcol + l15) * BK + sx_];           \
            short8 bfr1 = *(const short8*)&Bb_[(wcol + 16 + l15) * BK + sx_];      \
            _Pragma("unroll")                                                      \
            for (int i = 0; i < MREP; ++i) {                                       \
                short8 af_ = *(const short8*)&Ab_[(wrow + i * 16 + l15) * BK + sx_]; \
                acc[i][0] = __builtin_amdgcn_mfma_f32_16x16x32_bf16(af_, bfr0, acc[i][0], 0, 0, 0); \
                acc[i][1] = __builtin_amdgcn_mfma_f32_16x16x32_bf16(af_, bfr1, acc[i][1], 0, 0, 0); \
            }                                                                      \
        }                                                                          \
    } while (0)

    STAGE_T(0, 0);
    STAGE_T(1, 1);

    int NT = K / BK;
    int cb = 0, nbuf = 2;
    for (int t = 0; t < NT - 2; ++t) {
        STAGE_T(t + 2, nbuf);
        if constexpr (AJ == 4) { S_WAITCNT_VM(12); } else { S_WAITCNT_VM(8); }
        __builtin_amdgcn_s_barrier();
        __builtin_amdgcn_s_setprio(1);
        COMPUTE_T(cb);
        __builtin_amdgcn_s_setprio(0);
        asm volatile("s_waitcnt lgkmcnt(0)" ::: "memory");
        __builtin_amdgcn_s_barrier();
        cb = (cb == 2) ? 0 : cb + 1;
        nbuf = (nbuf == 2) ? 0 : nbuf + 1;
    }
    if constexpr (AJ == 4) { S_WAITCNT_VM(6); } else { S_WAITCNT_VM(4); }
    __builtin_amdgcn_s_barrier();
    __builtin_amdgcn_s_setprio(1);
    COMPUTE_T(cb);
    __builtin_amdgcn_s_setprio(0);
    asm volatile("s_waitcnt lgkmcnt(0)" ::: "memory");
    __builtin_amdgcn_s_barrier();
    cb = (cb == 2) ? 0 : cb + 1;
    S_WAITCNT_VM(0);
    __builtin_amdgcn_s_barrier();
    COMPUTE_T(cb);

    #undef STAGE_T
    #undef COMPUTE_T

    int rbase = quad * 4;
    #pragma unroll
    for (int i = 0; i < MREP; ++i) {
        #pragma unroll
        for (int n = 0; n < 2; ++n) {
            int gc = n0 + wcol + n * 16 + l15;
            float bv = bias[gc];
            int gr = m0 + wrow + i * 16 + rbase;
            #pragma unroll
            for (int reg = 0; reg < 4; ++reg) {
                if constexpr (EPI == 0) {
                    ((ushort*)Cout)[(size_t)(gr + reg) * N + gc] =
                        f2bf(fast_gelu(acc[i][n][reg] + bv));
                } else if constexpr (EPI == 1) {
                    ((float*)Cout)[(size_t)(gr + reg) * N + gc] = acc[i][n][reg] + bv;
                } else {
                    float* xp = (float*)Cout + (size_t)(gr + reg) * N + gc;
                    *xp = *xp + acc[i][n][reg] + bv;
                }
            }
        }
    }
}

// ---------------- CLS-only final layer (r6-verified, parallelized) ----------------
__global__ __launch_bounds__(256) void ln_cls_kernel(const float* __restrict__ x,
                                                     const float* __restrict__ g,
                                                     const float* __restrict__ bb,
                                                     ushort* __restrict__ h2c) {
    int lane = threadIdx.x & 63;
    int r = blockIdx.x * 4 + (threadIdx.x >> 6);
    const float* xr = x + (size_t)r * T * D + lane * 8;
    float4 a0 = *(const float4*)xr;
    float4 a1 = *(const float4*)(xr + 4);
    float s = a0.x + a0.y + a0.z + a0.w + a1.x + a1.y + a1.z + a1.w;
    #pragma unroll
    for (int off = 1; off < 64; off <<= 1) s += __shfl_xor(s, off);
    float mean = s * (1.0f / (float)D);
    float d0 = a0.x - mean, d1 = a0.y - mean, d2 = a0.z - mean, d3 = a0.w - mean;
    float d4 = a1.x - mean, d5 = a1.y - mean, d6 = a1.z - mean, d7 = a1.w - mean;
    float sq = d0*d0 + d1*d1 + d2*d2 + d3*d3 + d4*d4 + d5*d5 + d6*d6 + d7*d7;
    #pragma unroll
    for (int off = 1; off < 64; off <<= 1) sq += __shfl_xor(sq, off);
    float rstd = rsqrtf(sq * (1.0f / (float)D) + EPS);
    const float* gp = g + lane * 8;
    const float* bp = bb + lane * 8;
    float4 g0 = *(const float4*)gp, g1 = *(const float4*)(gp + 4);
    float4 b0 = *(const float4*)bp, b1v = *(const float4*)(bp + 4);
    short8 o;
    o[0] = (short)f2bf(d0 * rstd * g0.x + b0.x);
    o[1] = (short)f2bf(d1 * rstd * g0.y + b0.y);
    o[2] = (short)f2bf(d2 * rstd * g0.z + b0.z);
    o[3] = (short)f2bf(d3 * rstd * g0.w + b0.w);
    o[4] = (short)f2bf(d4 * rstd * g1.x + b1v.x);
    o[5] = (short)f2bf(d5 * rstd * g1.y + b1v.y);
    o[6] = (short)f2bf(d6 * rstd * g1.z + b1v.z);
    o[7] = (short)f2bf(d7 * rstd * g1.w + b1v.w);
    *(short8*)(h2c + r * D + lane * 8) = o;
}

__global__ __launch_bounds__(256) void gemm1_cls(const ushort* __restrict__ h2c,
                                                 const ushort* __restrict__ W1t,
                                                 const float* __restrict__ b1,
                                                 ushort* __restrict__ uc) {
    int tid = threadIdx.x;
    int lane = tid & 63;
    int w = __builtin_amdgcn_readfirstlane(tid >> 6);
    int quad = lane >> 4, l15 = lane & 15;
    int nb = blockIdx.x * 64 + w * 16;

    short8 af[16];
    #pragma unroll
    for (int ks = 0; ks < 16; ++ks)
        af[ks] = *(const short8*)&h2c[l15 * D + ks * 32 + quad * 8];

    const ushort* wrow = W1t + (size_t)(nb + l15) * D + quad * 8;
    floatx4 acc = (floatx4)0.f;
    #pragma unroll
    for (int ks = 0; ks < 16; ++ks) {
        short8 bf = *(const short8*)(wrow + ks * 32);
        acc = __builtin_amdgcn_mfma_f32_16x16x32_bf16(af[ks], bf, acc, 0, 0, 0);
    }
    float bv = b1[nb + l15];
    #pragma unroll
    for (int reg = 0; reg < 4; ++reg)
        uc[(size_t)(quad * 4 + reg) * MLPD + nb + l15] = f2bf(fast_gelu(acc[reg] + bv));
}

__global__ __launch_bounds__(256) void gemm2_cls(const ushort* __restrict__ uc,
                                                 const ushort* __restrict__ W2t,
                                                 const float* __restrict__ b2,
                                                 float* __restrict__ p0c) {
    __shared__ float red[4 * 256];
    int tid = threadIdx.x;
    int lane = tid & 63;
    int w = __builtin_amdgcn_readfirstlane(tid >> 6);
    int quad = lane >> 4, l15 = lane & 15;
    int nb = blockIdx.x * 16;

    const ushort* wrow = W2t + (size_t)(nb + l15) * MLPD + quad * 8;
    floatx4 acc = (floatx4)0.f;
    #pragma unroll
    for (int k8 = 0; k8 < 16; ++k8) {
        int ks = w * 16 + k8;
        short8 a2 = *(const short8*)&uc[(size_t)l15 * MLPD + ks * 32 + quad * 8];
        short8 bf = *(const short8*)(wrow + (size_t)ks * 32);
        acc = __builtin_amdgcn_mfma_f32_16x16x32_bf16(a2, bf, acc, 0, 0, 0);
    }
    #pragma unroll
    for (int reg = 0; reg < 4; ++reg)
        red[w * 256 + (quad * 4 + reg) * 16 + l15] = acc[reg];
    __syncthreads();
    int row = tid >> 4, col = tid & 15;
    float s = red[row * 16 + col] + red[256 + row * 16 + col]
            + red[512 + row * 16 + col] + red[768 + row * 16 + col];
    p0c[(size_t)row * D + nb + col] = s + b2[nb + col];
}

// ---------------- head: out[b] = sigmoid((x[b,0]+p0c[b]) . head_W + head_b) ----------------
__global__ void head_kernel(const float* __restrict__ x,
                            const float* __restrict__ p0c,
                            const float* __restrict__ hw,
                            const float* __restrict__ hb,
                            float* __restrict__ out) {
    int b = blockIdx.x;
    int tid = threadIdx.x; // 512
    float s = (x[(size_t)b * T * D + tid] + p0c[(size_t)b * D + tid]) * hw[tid];
    #pragma unroll
    for (int off = 32; off > 0; off >>= 1) s += __shfl_down(s, off, 64);
    __shared__ float red[8];
    if ((tid & 63) == 0) red[tid >> 6] = s;
    __syncthreads();
    if (tid == 0) {
        float t = 0.f;
        #pragma unroll
        for (int i = 0; i < 8; ++i) t += red[i];
        out[b] = 1.0f / (1.0f + __expf(-(t + hb[0])));
    }
}

extern "C" void kernel_launch(void* const* d_in, const int* in_sizes, int n_in,
                              void* d_out, int out_size, void* d_ws, size_t ws_size,
                              hipStream_t stream) {
    const float* src     = (const float*)d_in[0];
    const float* emb_W   = (const float*)d_in[1];
    const float* emb_b   = (const float*)d_in[2];
    const float* cls_tok = (const float*)d_in[3];
    const float* ln1_g   = (const float*)d_in[4];
    const float* ln1_b   = (const float*)d_in[5];
    const float* Wq      = (const float*)d_in[6];
    const float* bq      = (const float*)d_in[7];
    const float* Wk      = (const float*)d_in[8];
    const float* bk      = (const float*)d_in[9];
    const float* Wv      = (const float*)d_in[10];
    const float* bv      = (const float*)d_in[11];
    const float* ln2_g   = (const float*)d_in[12];
    const float* ln2_b   = (const float*)d_in[13];
    const float* W1      = (const float*)d_in[14];
    const float* b1      = (const float*)d_in[15];
    const float* W2      = (const float*)d_in[16];
    const float* b2      = (const float*)d_in[17];
    const float* head_W  = (const float*)d_in[18];
    const float* head_b  = (const float*)d_in[19];

    const size_t NTOK = (size_t)B * T;          // 8192
    char* wsb = (char*)d_ws;
    float*  x    = (float*)wsb;      wsb += NTOK * D * 4;
    ushort* hbuf = (ushort*)wsb;     wsb += NTOK * D * 2;
    ushort* q    = (ushort*)wsb;     wsb += NTOK * D * 2;
    ushort* k    = (ushort*)wsb;     wsb += NTOK * D * 2;
    ushort* vT   = (ushort*)wsb;     wsb += NTOK * D * 2;
    ushort* u    = (ushort*)wsb;     wsb += NTOK * MLPD * 2;
    ushort* W1t  = (ushort*)wsb;     wsb += (size_t)NB * D * MLPD * 2;
    ushort* W2t  = (ushort*)wsb;     wsb += (size_t)NB * D * MLPD * 2;
    ushort* WqT  = (ushort*)wsb;     wsb += (size_t)NB * H * DH * DH * 2;
    ushort* WkT  = (ushort*)wsb;     wsb += (size_t)NB * H * DH * DH * 2;
    ushort* WvT  = (ushort*)wsb;     wsb += (size_t)NB * H * DH * DH * 2;
    ushort* srcb = (ushort*)wsb;     wsb += NTOK * F * 2;
    ushort* embWt= (ushort*)wsb;     wsb += (size_t)F * D * 2;
    ushort* h2c  = (ushort*)wsb;     wsb += (size_t)16 * D * 2;
    ushort* ucls = (ushort*)wsb;     wsb += (size_t)16 * MLPD * 2;
    float*  p0c  = (float*)wsb;      wsb += (size_t)16 * D * 4;

    // weight / input prep (every launch)
    wtrans_kernel<<<dim3(D / 32, MLPD / 32, NB), 256, 0, stream>>>(W1, W1t, D, MLPD);
    wtrans_kernel<<<dim3(MLPD / 32, D / 32, NB), 256, 0, stream>>>(W2, W2t, MLPD, D);
    wtransq_kernel<<<dim3(NB * H, 3), 256, 0, stream>>>(Wq, Wk, Wv, WqT, WkT, WvT);
    wtrans_kernel<<<dim3(F / 32, D / 32, 1), 256, 0, stream>>>(emb_W, embWt, F, D);
    castsrc_kernel<<<B * T, F, 0, stream>>>(src, srcb);

    embed_gemm<<<dim3(B * T / 64, D / 64), 256, 0, stream>>>(srcb, embWt, emb_b, cls_tok, x);

    for (int i = 0; i < NB; ++i) {
        lnqkv_kernel<<<B * T / 32, 256, 0, stream>>>(x,
            ln1_g + i * D, ln1_b + i * D,
            WqT + (size_t)i * H * DH * DH, bq + (size_t)i * H * DH,
            WkT + (size_t)i * H * DH * DH, bk + (size_t)i * H * DH,
            WvT + (size_t)i * H * DH * DH, bv + (size_t)i * H * DH,
            q, k, vT);
        if (i < NB - 1) {
            attn_kernel<<<dim3(T / 64, B * H), 256, 0, stream>>>(q, k, vT, x);
            ln_kernel<<<B * T / 4, 256, 0, stream>>>(x, ln2_g + i * D, ln2_b + i * D, hbuf);
            gemm1_8p<<<dim3((B * T / 256) * (MLPD / 256)), 512, 0, stream>>>(
                hbuf, W1t + (size_t)i * D * MLPD, b1 + (size_t)i * MLPD, u, MLPD, D);
            gemm_pipe<128, 2><<<dim3(B * T / 128, D / 128), 512, 0, stream>>>(
                u, W2t + (size_t)i * MLPD * D, b2 + (size_t)i * D, x, D, MLPD);
        } else {
            attn_kernel<<<dim3(1, B * H), 256, 0, stream>>>(q, k, vT, x);
            ln_cls_kernel<<<4, 256, 0, stream>>>(x,
                ln2_g + (size_t)i * D, ln2_b + (size_t)i * D, h2c);
            gemm1_cls<<<MLPD / 64, 256, 0, stream>>>(h2c,
                W1t + (size_t)i * D * MLPD, b1 + (size_t)i * MLPD, ucls);
            gemm2_cls<<<D / 16, 256, 0, stream>>>(ucls,
                W2t + (size_t)i * MLPD * D, b2 + (size_t)i * D, p0c);
            head_kernel<<<B, 512, 0, stream>>>(x, p0c, head_W, head_b, (float*)d_out);
        }
    }
}

// Round 10
// 752.307 us; speedup vs baseline: 1.0516x; 1.0516x over previous
//
#include <hip/hip_runtime.h>
#include <hip/hip_bf16.h>
#include <math.h>

#define B 16
#define S 511
#define F 128
#define D 512
#define H 8
#define NB 6
#define DH 64
#define MLPD 2048
#define T 512
#define EPS 1e-5f

typedef unsigned short ushort;
typedef __attribute__((ext_vector_type(8))) short short8;
typedef __attribute__((ext_vector_type(4))) float floatx4;

__device__ __forceinline__ ushort f2bf(float f) {
    union { float f; unsigned u; } cv; cv.f = f;
    unsigned r = (cv.u + 0x7fff + ((cv.u >> 16) & 1)) >> 16;  // RNE
    return (ushort)r;
}

// Branch-free erf (Abramowitz-Stegun 7.1.26, |err| <= 1.5e-7)
__device__ __forceinline__ float fast_gelu(float x) {
    float z = fabsf(x) * 0.70710678118f;
    float t = 1.0f / (1.0f + 0.3275911f * z);
    float p = ((((1.061405429f * t - 1.453152027f) * t + 1.421413741f) * t
               - 0.284496736f) * t + 0.254829592f) * t;
    float erfv = 1.0f - p * __expf(-z * z);
    erfv = copysignf(erfv, x);
    return 0.5f * x * (1.0f + erfv);
}

// ---------------- cast src -> bf16 A-matrix for embed GEMM (t=0 rows zeroed) ----------------
__global__ void castsrc_kernel(const float* __restrict__ src, ushort* __restrict__ srcb) {
    int row = blockIdx.x;              // b*T + t
    int t = row & (T - 1), b = row >> 9;
    int tid = threadIdx.x;             // 128
    ushort v = 0;
    if (t > 0) v = f2bf(src[((size_t)b * S + (t - 1)) * F + tid]);
    srcb[(size_t)row * F + tid] = v;
}

// ---------------- generic transpose+cast: W [mat,K,N] fp32 -> Wt [mat,N,K] bf16 ----------------
__global__ void wtrans_kernel(const float* __restrict__ W,
                              ushort* __restrict__ Wt,
                              int K, int N) {
    int kb = blockIdx.x * 32, nb = blockIdx.y * 32, mat = blockIdx.z;
    __shared__ float tile[32][33];
    int tid = threadIdx.x; // 256
    int c = tid & 31, r0 = tid >> 5;
    const float* Wm = W + (size_t)mat * K * N;
    ushort* Wtm = Wt + (size_t)mat * K * N;
    #pragma unroll
    for (int l = 0; l < 4; ++l) {
        int r = r0 + l * 8;
        tile[r][c] = Wm[(size_t)(kb + r) * N + nb + c];
    }
    __syncthreads();
    #pragma unroll
    for (int l = 0; l < 4; ++l) {
        int r = r0 + l * 8;
        Wtm[(size_t)(nb + r) * K + kb + c] = f2bf(tile[c][r]);
    }
}

// ---------------- qkv weight transpose+cast ----------------
__global__ void wtransq_kernel(const float* __restrict__ Wq, const float* __restrict__ Wk,
                               const float* __restrict__ Wv,
                               ushort* __restrict__ WqT, ushort* __restrict__ WkT,
                               ushort* __restrict__ WvT) {
    int mat = blockIdx.x;          // 0..NB*H-1
    int which = blockIdx.y;        // 0,1,2
    const float* W = (which == 0 ? Wq : which == 1 ? Wk : Wv) + (size_t)mat * 4096;
    ushort* O = (which == 0 ? WqT : which == 1 ? WkT : WvT) + (size_t)mat * 4096;
    __shared__ float t[64][65];
    int tid = threadIdx.x;  // 256
    int r0 = tid >> 6, c = tid & 63;
    #pragma unroll
    for (int l = 0; l < 16; ++l) {
        int row = r0 * 16 + l;
        t[row][c] = W[row * 64 + c];
    }
    __syncthreads();
    #pragma unroll
    for (int l = 0; l < 16; ++l) {
        int row = r0 * 16 + l;
        O[row * 64 + c] = f2bf(t[c][row]);
    }
}

// ---------------- async global->LDS helper ----------------
__device__ __forceinline__ void gload_lds16(const ushort* g, ushort* l) {
    __builtin_amdgcn_global_load_lds((const __attribute__((address_space(1))) unsigned int*)g,
                                     (__attribute__((address_space(3))) unsigned int*)l,
                                     16, 0, 0);
}

#define S_WAITCNT_VM(N) asm volatile("s_waitcnt vmcnt(" #N ")" ::: "memory")
#define S_WAITCNT_LGKM0 asm volatile("s_waitcnt lgkmcnt(0)" ::: "memory")
#define S_WAITCNT_LGKM8 asm volatile("s_waitcnt lgkmcnt(8)" ::: "memory")

// ---------------- embed GEMM: x = concat(cls, srcb@embWt^T)+emb_b+pe, fp32 out ----------------
__global__ __launch_bounds__(256) void embed_gemm(const ushort* __restrict__ A,
                                                  const ushort* __restrict__ Bt,
                                                  const float* __restrict__ emb_b,
                                                  const float* __restrict__ cls_tok,
                                                  float* __restrict__ x) {
    __shared__ ushort As[64 * 32];
    __shared__ ushort Bs[64 * 32];
    int tid = threadIdx.x;
    int lane = tid & 63;
    int w = __builtin_amdgcn_readfirstlane(tid >> 6);
    int quad = lane >> 4, l15 = lane & 15;
    int wr = (w >> 1) * 32, wc = (w & 1) * 32;
    int m0 = blockIdx.x * 64, n0 = blockIdx.y * 64;

    floatx4 acc[2][2];
    #pragma unroll
    for (int i = 0; i < 2; ++i)
        #pragma unroll
        for (int j = 0; j < 2; ++j) acc[i][j] = (floatx4)0.f;

    int lrow = lane >> 2;
    int lk = (lane & 3) * 8;
    const ushort* Ag = A + (size_t)(m0 + 16 * w + lrow) * F + lk;
    const ushort* Bg = Bt + (size_t)(n0 + 16 * w + lrow) * F + lk;
    ushort* AsW = &As[16 * w * 32];
    ushort* BsW = &Bs[16 * w * 32];
    int fa = l15 * 32 + quad * 8;

    for (int kt = 0; kt < F; kt += 32) {
        gload_lds16(Ag + kt, AsW);
        gload_lds16(Bg + kt, BsW);
        __syncthreads();
        short8 af[2], bf[2];
        #pragma unroll
        for (int i = 0; i < 2; ++i) af[i] = *(const short8*)&As[(wr + 16 * i) * 32 + fa];
        #pragma unroll
        for (int j = 0; j < 2; ++j) bf[j] = *(const short8*)&Bs[(wc + 16 * j) * 32 + fa];
        #pragma unroll
        for (int i = 0; i < 2; ++i)
            #pragma unroll
            for (int j = 0; j < 2; ++j)
                acc[i][j] = __builtin_amdgcn_mfma_f32_16x16x32_bf16(af[i], bf[j], acc[i][j], 0, 0, 0);
        __syncthreads();
    }

    const float LOG1E4 = 9.210340371976184f;
    int rbase = (lane >> 4) * 4;
    int cidx = lane & 15;
    #pragma unroll
    for (int j = 0; j < 2; ++j) {
        int gc = n0 + wc + 16 * j + cidx;
        float je = (float)(gc & ~1);
        float freq = expf(-(je / (float)D) * LOG1E4);
        float ebv = emb_b[gc];
        float clsv = cls_tok[gc];
        bool odd = (gc & 1);
        #pragma unroll
        for (int i = 0; i < 2; ++i) {
            int gr = m0 + wr + 16 * i + rbase;
            #pragma unroll
            for (int reg = 0; reg < 4; ++reg) {
                int row = gr + reg;
                int t = row & (T - 1);
                float ang = (float)t * freq;
                float pe = odd ? cosf(ang) : sinf(ang);
                float val = (t == 0) ? (clsv + pe) : (acc[i][j][reg] + ebv + pe);
                x[(size_t)row * D + gc] = val;
            }
        }
    }
}

// ---------------- layernorm -> bf16: one wave per row, shuffle-only ----------------
__global__ __launch_bounds__(256) void ln_kernel(const float* __restrict__ xin,
                                                 const float* __restrict__ g,
                                                 const float* __restrict__ bb,
                                                 ushort* __restrict__ out) {
    int lane = threadIdx.x & 63;
    int row = blockIdx.x * 4 + (threadIdx.x >> 6);
    const float* xr = xin + (size_t)row * D + lane * 8;
    float4 a0 = *(const float4*)xr;
    float4 a1 = *(const float4*)(xr + 4);
    float s = a0.x + a0.y + a0.z + a0.w + a1.x + a1.y + a1.z + a1.w;
    #pragma unroll
    for (int off = 1; off < 64; off <<= 1) s += __shfl_xor(s, off);
    float mean = s * (1.0f / (float)D);
    float d0 = a0.x - mean, d1 = a0.y - mean, d2 = a0.z - mean, d3 = a0.w - mean;
    float d4 = a1.x - mean, d5 = a1.y - mean, d6 = a1.z - mean, d7 = a1.w - mean;
    float sq = d0*d0 + d1*d1 + d2*d2 + d3*d3 + d4*d4 + d5*d5 + d6*d6 + d7*d7;
    #pragma unroll
    for (int off = 1; off < 64; off <<= 1) sq += __shfl_xor(sq, off);
    float rstd = rsqrtf(sq * (1.0f / (float)D) + EPS);
    const float* gp = g + lane * 8;
    const float* bp = bb + lane * 8;
    float4 g0 = *(const float4*)gp, g1 = *(const float4*)(gp + 4);
    float4 b0 = *(const float4*)bp, b1 = *(const float4*)(bp + 4);
    short8 o;
    o[0] = (short)f2bf(d0 * rstd * g0.x + b0.x);
    o[1] = (short)f2bf(d1 * rstd * g0.y + b0.y);
    o[2] = (short)f2bf(d2 * rstd * g0.z + b0.z);
    o[3] = (short)f2bf(d3 * rstd * g0.w + b0.w);
    o[4] = (short)f2bf(d4 * rstd * g1.x + b1.x);
    o[5] = (short)f2bf(d5 * rstd * g1.y + b1.y);
    o[6] = (short)f2bf(d6 * rstd * g1.z + b1.z);
    o[7] = (short)f2bf(d7 * rstd * g1.w + b1.w);
    *(short8*)(out + (size_t)row * D + lane * 8) = o;
}

// ---------------- fused LN1 + QKV: 32-row block; LN into padded LDS, then per-head MFMA ------
#define LQPAD 520
__global__ __launch_bounds__(256) void lnqkv_kernel(
        const float* __restrict__ x,
        const float* __restrict__ g, const float* __restrict__ bb,
        const ushort* __restrict__ WqT, const float* __restrict__ bq,
        const ushort* __restrict__ WkT, const float* __restrict__ bk,
        const ushort* __restrict__ WvT, const float* __restrict__ bv,
        ushort* __restrict__ qo, ushort* __restrict__ ko, ushort* __restrict__ vTo) {
    __shared__ ushort hl[32 * LQPAD];   // 33.3 KB
    int tid = threadIdx.x;
    int lane = tid & 63;
    int w = __builtin_amdgcn_readfirstlane(tid >> 6);   // 0..3
    int quad = lane >> 4, l15 = lane & 15;
    int m0 = blockIdx.x * 32;

    for (int it = 0; it < 8; ++it) {
        int lr = it * 4 + w;
        const float* xr = x + (size_t)(m0 + lr) * D + lane * 8;
        float4 a0 = *(const float4*)xr;
        float4 a1 = *(const float4*)(xr + 4);
        float s = a0.x + a0.y + a0.z + a0.w + a1.x + a1.y + a1.z + a1.w;
        #pragma unroll
        for (int off = 1; off < 64; off <<= 1) s += __shfl_xor(s, off);
        float mean = s * (1.0f / (float)D);
        float d0 = a0.x - mean, d1 = a0.y - mean, d2 = a0.z - mean, d3 = a0.w - mean;
        float d4 = a1.x - mean, d5 = a1.y - mean, d6 = a1.z - mean, d7 = a1.w - mean;
        float sq = d0*d0 + d1*d1 + d2*d2 + d3*d3 + d4*d4 + d5*d5 + d6*d6 + d7*d7;
        #pragma unroll
        for (int off = 1; off < 64; off <<= 1) sq += __shfl_xor(sq, off);
        float rstd = rsqrtf(sq * (1.0f / (float)D) + EPS);
        const float* gp = g + lane * 8;
        const float* bp = bb + lane * 8;
        float4 g0 = *(const float4*)gp, g1 = *(const float4*)(gp + 4);
        float4 b0 = *(const float4*)bp, b1v = *(const float4*)(bp + 4);
        short8 o;
        o[0] = (short)f2bf(d0 * rstd * g0.x + b0.x);
        o[1] = (short)f2bf(d1 * rstd * g0.y + b0.y);
        o[2] = (short)f2bf(d2 * rstd * g0.z + b0.z);
        o[3] = (short)f2bf(d3 * rstd * g0.w + b0.w);
        o[4] = (short)f2bf(d4 * rstd * g1.x + b1v.x);
        o[5] = (short)f2bf(d5 * rstd * g1.y + b1v.y);
        o[6] = (short)f2bf(d6 * rstd * g1.z + b1v.z);
        o[7] = (short)f2bf(d7 * rstd * g1.w + b1v.w);
        *(short8*)(hl + lr * LQPAD + lane * 8) = o;
    }
    __syncthreads();

    int bb_ = m0 >> 9;
    #pragma unroll
    for (int hp = 0; hp < 2; ++hp) {
        int hh = w * 2 + hp;
        short8 af[2][2];
        #pragma unroll
        for (int mt = 0; mt < 2; ++mt)
            #pragma unroll
            for (int ks = 0; ks < 2; ++ks)
                af[mt][ks] = *(const short8*)&hl[(mt * 16 + l15) * LQPAD + hh * DH + ks * 32 + quad * 8];

        floatx4 acc[3][2][4];
        #pragma unroll
        for (int xo = 0; xo < 3; ++xo)
            #pragma unroll
            for (int mt = 0; mt < 2; ++mt)
                #pragma unroll
                for (int nt = 0; nt < 4; ++nt) acc[xo][mt][nt] = (floatx4)0.f;

        #pragma unroll
        for (int xo = 0; xo < 3; ++xo) {
            const ushort* WT = (xo == 0 ? WqT : xo == 1 ? WkT : WvT) + (size_t)hh * 4096;
            #pragma unroll
            for (int nt = 0; nt < 4; ++nt) {
                const ushort* wb = WT + (size_t)(nt * 16 + l15) * 64 + quad * 8;
                short8 bf0 = *(const short8*)(wb);
                short8 bf1 = *(const short8*)(wb + 32);
                #pragma unroll
                for (int mt = 0; mt < 2; ++mt) {
                    acc[xo][mt][nt] = __builtin_amdgcn_mfma_f32_16x16x32_bf16(af[mt][0], bf0, acc[xo][mt][nt], 0, 0, 0);
                    acc[xo][mt][nt] = __builtin_amdgcn_mfma_f32_16x16x32_bf16(af[mt][1], bf1, acc[xo][mt][nt], 0, 0, 0);
                }
            }
        }

        int bh = bb_ * H + hh;
        #pragma unroll
        for (int mt = 0; mt < 2; ++mt) {
            int trow = m0 + mt * 16 + quad * 4;
            int tt = trow & (T - 1);
            #pragma unroll
            for (int nt = 0; nt < 4; ++nt) {
                int col = nt * 16 + l15;
                float bqv = bq[hh * DH + col];
                float bkv = bk[hh * DH + col];
                float bvv = bv[hh * DH + col];
                #pragma unroll
                for (int reg = 0; reg < 4; ++reg) {
                    qo[((size_t)bh * T + tt + reg) * DH + col] = f2bf(acc[0][mt][nt][reg] + bqv);
                    ko[((size_t)bh * T + tt + reg) * DH + col] = f2bf(acc[1][mt][nt][reg] + bkv);
                    vTo[((size_t)bh * DH + col) * T + tt + reg] = f2bf(acc[2][mt][nt][reg] + bvv);
                }
            }
        }
    }
}

// ---------------- MFMA flash attention (r8-exact: scalar f2bf softmax, grid (bh, qt)) --------
#define PSTRIDE 88
__global__ __launch_bounds__(256) void attn_kernel(const ushort* __restrict__ q,
                                                   const ushort* __restrict__ k,
                                                   const ushort* __restrict__ vT,
                                                   float* __restrict__ x) {
    int bh = blockIdx.x;
    int qt = blockIdx.y;
    int b = bh >> 3, hh = bh & 7;
    int tid = threadIdx.x;
    int lane = tid & 63;
    int w = __builtin_amdgcn_readfirstlane(tid >> 6);   // 0..3
    int quad = lane >> 4, l15 = lane & 15;

    __shared__ __align__(16) ushort smem[22016];   // 44032 B
    ushort* Pw = smem + 16384 + w * (16 * PSTRIDE);

    const ushort* qbase = q + ((size_t)bh * T + qt * 64 + w * 16 + l15) * DH + quad * 8;
    short8 Qf0 = *(const short8*)(qbase);
    short8 Qf1 = *(const short8*)(qbase + 32);

    const ushort* kbase = k + (size_t)bh * T * DH;
    const ushort* vbase = vT + (size_t)bh * DH * T;

    int srow = lane >> 2;
    int scol = (lane & 3) * 8;
    const ushort* kg = kbase + (size_t)(w * 16 + srow) * DH + scol;
    const ushort* vg = vbase + (size_t)(w * 16 + srow) * T + scol;
    ushort* ldsK = smem + w * 16 * 32;
    ushort* ldsV = smem + 8192 + w * 16 * 32;

    float l_i[4] = {0.f, 0.f, 0.f, 0.f};
    floatx4 O[4];
    #pragma unroll
    for (int j = 0; j < 4; ++j) O[j] = (floatx4)0.f;

    gload_lds16(kg, ldsK);
    gload_lds16(kg + 32, ldsK + 2048);
    gload_lds16(vg, ldsV);
    gload_lds16(vg + 32, ldsV + 2048);
    __syncthreads();

    for (int kt = 0; kt < T / 64; ++kt) {
        int cur = kt & 1;
        if (kt < T / 64 - 1) {
            int nb = cur ^ 1;
            const ushort* kgn = kg + (size_t)(kt + 1) * 64 * DH;
            const ushort* vgn = vg + (kt + 1) * 64;
            gload_lds16(kgn, ldsK + nb * 4096);
            gload_lds16(kgn + 32, ldsK + nb * 4096 + 2048);
            gload_lds16(vgn, ldsV + nb * 4096);
            gload_lds16(vgn + 32, ldsV + nb * 4096 + 2048);
        }
        const ushort* Kc = smem + cur * 4096;
        const ushort* Vc = smem + 8192 + cur * 4096;

        floatx4 sc[4];
        __builtin_amdgcn_s_setprio(1);
        #pragma unroll
        for (int j = 0; j < 4; ++j) {
            int ro = (j * 16 + l15) * 32 + quad * 8;
            short8 kf0 = *(const short8*)&Kc[ro];
            short8 kf1 = *(const short8*)&Kc[2048 + ro];
            floatx4 s4 = (floatx4)0.f;
            s4 = __builtin_amdgcn_mfma_f32_16x16x32_bf16(Qf0, kf0, s4, 0, 0, 0);
            s4 = __builtin_amdgcn_mfma_f32_16x16x32_bf16(Qf1, kf1, s4, 0, 0, 0);
            sc[j] = s4;
        }
        __builtin_amdgcn_s_setprio(0);
        #pragma unroll
        for (int j = 0; j < 4; ++j) {
            #pragma unroll
            for (int r = 0; r < 4; ++r) {
                float p = __expf(sc[j][r] * 0.125f);
                l_i[r] += p;
                Pw[(quad * 4 + r) * PSTRIDE + j * 16 + l15] = f2bf(p);
            }
        }

        short8 af0 = *(const short8*)&Pw[l15 * PSTRIDE + quad * 8];
        short8 af1 = *(const short8*)&Pw[l15 * PSTRIDE + 32 + quad * 8];
        __builtin_amdgcn_s_setprio(1);
        #pragma unroll
        for (int j = 0; j < 4; ++j) {
            int ro = (j * 16 + l15) * 32 + quad * 8;
            short8 vf0 = *(const short8*)&Vc[ro];
            short8 vf1 = *(const short8*)&Vc[2048 + ro];
            O[j] = __builtin_amdgcn_mfma_f32_16x16x32_bf16(af0, vf0, O[j], 0, 0, 0);
            O[j] = __builtin_amdgcn_mfma_f32_16x16x32_bf16(af1, vf1, O[j], 0, 0, 0);
        }
        __builtin_amdgcn_s_setprio(0);
        __syncthreads();
    }

    #pragma unroll
    for (int r = 0; r < 4; ++r) {
        l_i[r] += __shfl_xor(l_i[r], 1);
        l_i[r] += __shfl_xor(l_i[r], 2);
        l_i[r] += __shfl_xor(l_i[r], 4);
        l_i[r] += __shfl_xor(l_i[r], 8);
    }

    float* Ow = (float*)smem + w * 16 * 68;
    #pragma unroll
    for (int r = 0; r < 4; ++r) {
        float rl = 1.0f / l_i[r];
        #pragma unroll
        for (int j = 0; j < 4; ++j)
            Ow[(quad * 4 + r) * 68 + j * 16 + l15] = O[j][r] * rl;
    }
    __syncthreads();
    int r4 = lane >> 4;
    int c16 = lane & 15;
    #pragma unroll
    for (int i = 0; i < 4; ++i) {
        int lrow = i * 4 + r4;
        float4 o = *(const float4*)&Ow[lrow * 68 + c16 * 4];
        int grow = qt * 64 + w * 16 + lrow;
        float* xp = &x[((size_t)(b * T) + grow) * D + hh * DH + c16 * 4];
        float4 xv = *(const float4*)xp;
        xv.x += o.x; xv.y += o.y; xv.z += o.z; xv.w += o.w;
        *(float4*)xp = xv;
    }
}

// ---------------- gemm1: m201-style 256x256 8-phase, BK=64, 2 K-tiles/iter, counted vmcnt ----
// (r8-verified; ledger in r8 commit message)
__global__ __launch_bounds__(512, 1) void gemm1_8p(const ushort* __restrict__ A,
                                                   const ushort* __restrict__ Bt,
                                                   const float* __restrict__ bias,
                                                   ushort* __restrict__ C,
                                                   int N, int K) {
    constexpr int BUF = 32768;
    constexpr int BOFS = 16384;
    __shared__ ushort lds[2 * BUF];

    int tid = threadIdx.x;
    int lane = tid & 63;
    int w = __builtin_amdgcn_readfirstlane(tid >> 6);
    int quad = lane >> 4, l15 = lane & 15;
    int wm = w >> 2, wn = w & 3;
    int wmr = wm * 128, wnr = wn * 64;

    int nwg = gridDim.x;
    int id = blockIdx.x;
    int idx = (id & 7) * (nwg >> 3) + (id >> 3);
    int NTg = N >> 8;
    int mt = idx / NTg, nt = idx - mt * NTg;
    int m0 = mt * 256, n0 = nt * 256;

    int strow = tid >> 3;
    int ssw = ((tid & 7) ^ (strow & 7)) * 8;
    const ushort* Ag = A + (size_t)(m0 + strow) * K + ssw;
    const ushort* Bg = Bt + (size_t)(n0 + strow) * K + ssw;
    int wdst = w << 9;

    int sx0 = (quad ^ (l15 & 7)) * 8;
    int sx1 = ((4 + quad) ^ (l15 & 7)) * 8;

    floatx4 acc[8][4];
    #pragma unroll
    for (int i = 0; i < 8; ++i)
        #pragma unroll
        for (int n = 0; n < 4; ++n) acc[i][n] = (floatx4)0.f;

    short8 a[4][2], b[4][2];

    #define STG_AH(h, t, bp) do {                                                         \
        gload_lds16(Ag + (size_t)((h) * 128) * K + (size_t)(t) * 64,                      \
                    (bp) + ((h) * 128) * 64 + wdst);                                      \
        gload_lds16(Ag + (size_t)((h) * 128 + 64) * K + (size_t)(t) * 64,                 \
                    (bp) + ((h) * 128 + 64) * 64 + wdst);                                 \
    } while (0)
    #define STG_BH(h, t, bp) do {                                                         \
        gload_lds16(Bg + (size_t)((h) * 128) * K + (size_t)(t) * 64,                      \
                    (bp) + BOFS + ((h) * 128) * 64 + wdst);                                \
        gload_lds16(Bg + (size_t)((h) * 128 + 64) * K + (size_t)(t) * 64,                 \
                    (bp) + BOFS + ((h) * 128 + 64) * 64 + wdst);                           \
    } while (0)

    #define RD_A03(bp) do { _Pragma("unroll")                                             \
        for (int ks = 0; ks < 2; ++ks) { int sx = ks ? sx1 : sx0;                         \
            _Pragma("unroll")                                                             \
            for (int i = 0; i < 4; ++i)                                                   \
                a[i][ks] = *(const short8*)&(bp)[(wmr + i * 16 + l15) * 64 + sx]; } } while (0)
    #define RD_A47(bp) do { _Pragma("unroll")                                             \
        for (int ks = 0; ks < 2; ++ks) { int sx = ks ? sx1 : sx0;                         \
            _Pragma("unroll")                                                             \
            for (int i = 0; i < 4; ++i)                                                   \
                a[i][ks] = *(const short8*)&(bp)[(wmr + (4 + i) * 16 + l15) * 64 + sx]; } } while (0)
    #define RD_B01(bp) do { _Pragma("unroll")                                             \
        for (int ks = 0; ks < 2; ++ks) { int sx = ks ? sx1 : sx0;                         \
            _Pragma("unroll")                                                             \
            for (int n = 0; n < 2; ++n)                                                   \
                b[n][ks] = *(const short8*)&(bp)[BOFS + (wnr + n * 16 + l15) * 64 + sx]; } } while (0)
    #define RD_B23(bp) do { _Pragma("unroll")                                             \
        for (int ks = 0; ks < 2; ++ks) { int sx = ks ? sx1 : sx0;                         \
            _Pragma("unroll")                                                             \
            for (int n = 0; n < 2; ++n)                                                   \
                b[2 + n][ks] = *(const short8*)&(bp)[BOFS + (wnr + (2 + n) * 16 + l15) * 64 + sx]; } } while (0)

    #define MFQ(mb, nb2) do { _Pragma("unroll")                                           \
        for (int ks = 0; ks < 2; ++ks)                                                    \
            _Pragma("unroll")                                                             \
            for (int i = 0; i < 4; ++i)                                                   \
                _Pragma("unroll")                                                         \
                for (int n = 0; n < 2; ++n)                                               \
                    acc[(mb) + i][(nb2) + n] = __builtin_amdgcn_mfma_f32_16x16x32_bf16(   \
                        a[i][ks], b[(nb2) + n][ks], acc[(mb) + i][(nb2) + n], 0, 0, 0); } while (0)

    #define BAR __builtin_amdgcn_s_barrier()
    #define PRIO_MFQ(mb, nb2) do { __builtin_amdgcn_s_setprio(1); MFQ(mb, nb2);           \
                                   __builtin_amdgcn_s_setprio(0); } while (0)

    ushort* buf0 = lds;
    ushort* buf1 = lds + BUF;

    STG_AH(0, 0, buf0); STG_AH(1, 0, buf0); STG_BH(0, 0, buf0); STG_BH(1, 0, buf0);
    STG_BH(0, 1, buf1); STG_BH(1, 1, buf1); STG_AH(0, 1, buf1);
    S_WAITCNT_VM(6);
    BAR;

    int NITER = K >> 7;
    int NT = K >> 6;
    for (int it = 0; it < NITER; ++it) {
        int t2 = 2 * it + 2, t3 = 2 * it + 3;
        bool s2 = (t2 < NT);
        RD_A03(buf0); RD_B01(buf0);
        STG_AH(1, 2 * it + 1, buf1);
        S_WAITCNT_LGKM8;
        BAR; S_WAITCNT_LGKM0; PRIO_MFQ(0, 0); BAR;
        RD_B23(buf0);
        BAR; S_WAITCNT_LGKM0; PRIO_MFQ(0, 2); BAR;
        RD_A47(buf0);
        if (s2) { STG_BH(0, t2, buf0); STG_BH(1, t2, buf0); }
        BAR; S_WAITCNT_LGKM0; PRIO_MFQ(4, 2); BAR;
        if (s2) { STG_AH(0, t2, buf0); S_WAITCNT_VM(6); } else { S_WAITCNT_VM(0); }
        BAR; PRIO_MFQ(4, 0); BAR;
        RD_A03(buf1); RD_B01(buf1);
        if (s2) STG_AH(1, t2, buf0);
        S_WAITCNT_LGKM8;
        BAR; S_WAITCNT_LGKM0; PRIO_MFQ(0, 0); BAR;
        RD_B23(buf1);
        BAR; S_WAITCNT_LGKM0; PRIO_MFQ(0, 2); BAR;
        RD_A47(buf1);
        if (s2) { STG_BH(0, t3, buf1); STG_BH(1, t3, buf1); }
        BAR; S_WAITCNT_LGKM0; PRIO_MFQ(4, 2); BAR;
        if (s2) { STG_AH(0, t3, buf1); S_WAITCNT_VM(6); }
        BAR; PRIO_MFQ(4, 0); BAR;
    }

    #undef STG_AH
    #undef STG_BH
    #undef RD_A03
    #undef RD_A47
    #undef RD_B01
    #undef RD_B23
    #undef MFQ
    #undef BAR
    #undef PRIO_MFQ

    int rbase = quad * 4;
    #pragma unroll
    for (int i = 0; i < 8; ++i) {
        #pragma unroll
        for (int n = 0; n < 4; ++n) {
            int gc = n0 + wnr + n * 16 + l15;
            float bv = bias[gc];
            int gr = m0 + wmr + i * 16 + rbase;
            #pragma unroll
            for (int reg = 0; reg < 4; ++reg) {
                C[(size_t)(gr + reg) * N + gc] = f2bf(fast_gelu(acc[i][n][reg] + bv));
            }
        }
    }
}

// ---------------- pipelined MFMA GEMM (gemm2, r1 bench-best): 3-buffer LDS, distance 2 ------
// EPI 2: C(fp32) += acc+bias (fused residual add).
template<int BM, int EPI>
__global__ __launch_bounds__(512) void gemm_pipe(const ushort* __restrict__ A,
                                                 const ushort* __restrict__ Bt,
                                                 const float* __restrict__ bias,
                                                 void* __restrict__ Cout,
                                                 int N, int K) {
    constexpr int BN = 128;
    constexpr int BK = 64;
    constexpr int MREP = BM / 32;
    constexpr int AJ = BM / 64;
    constexpr int TILE = (BM + BN) * BK;
    __shared__ ushort lds[3 * TILE];

    int tid = threadIdx.x;
    int lane = tid & 63;
    int w = __builtin_amdgcn_readfirstlane(tid >> 6);
    int quad = lane >> 4, l15 = lane & 15;
    int wrow = (w >> 2) * (BM / 2);
    int wcol = (w & 3) * 32;
    int m0 = blockIdx.x * BM, n0 = blockIdx.y * BN;

    int lrow8 = lane >> 3;
    int lslot = lane & 7;
    int scol = (lslot ^ lrow8) * 8;
    const ushort* Asrc = A + (size_t)(m0 + w * 8 + lrow8) * K + scol;
    const ushort* Bsrc = Bt + (size_t)(n0 + w * 8 + lrow8) * K + scol;
    ushort* ldsA0 = lds + (w * 8) * BK;
    ushort* ldsB0 = lds + BM * BK + (w * 8) * BK;

    int sx0 = ((quad) ^ (l15 & 7)) * 8;
    int sx1 = ((4 + quad) ^ (l15 & 7)) * 8;

    floatx4 acc[MREP][2];
    #pragma unroll
    for (int i = 0; i < MREP; ++i) {
        acc[i][0] = (floatx4)0.f;
        acc[i][1] = (floatx4)0.f;
    }

    #define STAGE_T(t, buf) do {                                                   \
        const ushort* ap_ = Asrc + (size_t)(t) * BK;                               \
        const ushort* bp_ = Bsrc + (size_t)(t) * BK;                               \
        ushort* la_ = ldsA0 + (buf) * TILE;                                        \
        ushort* lb_ = ldsB0 + (buf) * TILE;                                        \
        _Pragma("unroll")                                                          \
        for (int j = 0; j < AJ; ++j)                                               \
            gload_lds16(ap_ + (size_t)j * 64 * K, la_ + j * 64 * BK);              \
        _Pragma("unroll")                                                          \
        for (int j = 0; j < 2; ++j)                                                \
            gload_lds16(bp_ + (size_t)j * 64 * K, lb_ + j * 64 * BK);              \
    } while (0)

    #define COMPUTE_T(buf) do {                                                    \
        const ushort* Ab_ = lds + (buf) * TILE;                                    \
        const ushort* Bb_ = Ab_ + BM * BK;                                         \
        _Pragma("unroll")                                                          \
        for (int ks = 0; ks < 2; ++ks) {                                           \
            int sx_ = ks ? sx1 : sx0;                                              \
            short8 bfr0 = *(const short8*)&Bb_[(wcol + l15) * BK + sx_];           \
            short8 bfr1 = *(const short8*)&Bb_[(wcol + 16 + l15) * BK + sx_];      \
            _Pragma("unroll")                                                      \
            for (int i = 0; i < MREP; ++i) {                                       \
                short8 af_ = *(const short8*)&Ab_[(wrow + i * 16 + l15) * BK + sx_]; \
                acc[i][0] = __builtin_amdgcn_mfma_f32_16x16x32_bf16(af_, bfr0, acc[i][0], 0, 0, 0); \
                acc[i][1] = __builtin_amdgcn_mfma_f32_16x16x32_bf16(af_, bfr1, acc[i][1], 0, 0, 0); \
            }                                                                      \
        }                                                                          \
    } while (0)

    STAGE_T(0, 0);
    STAGE_T(1, 1);

    int NT = K / BK;
    int cb = 0, nbuf = 2;
    for (int t = 0; t < NT - 2; ++t) {
        STAGE_T(t + 2, nbuf);
        if constexpr (AJ == 4) { S_WAITCNT_VM(12); } else { S_WAITCNT_VM(8); }
        __builtin_amdgcn_s_barrier();
        __builtin_amdgcn_s_setprio(1);
        COMPUTE_T(cb);
        __builtin_amdgcn_s_setprio(0);
        asm volatile("s_waitcnt lgkmcnt(0)" ::: "memory");
        __builtin_amdgcn_s_barrier();
        cb = (cb == 2) ? 0 : cb + 1;
        nbuf = (nbuf == 2) ? 0 : nbuf + 1;
    }
    if constexpr (AJ == 4) { S_WAITCNT_VM(6); } else { S_WAITCNT_VM(4); }
    __builtin_amdgcn_s_barrier();
    __builtin_amdgcn_s_setprio(1);
    COMPUTE_T(cb);
    __builtin_amdgcn_s_setprio(0);
    asm volatile("s_waitcnt lgkmcnt(0)" ::: "memory");
    __builtin_amdgcn_s_barrier();
    cb = (cb == 2) ? 0 : cb + 1;
    S_WAITCNT_VM(0);
    __builtin_amdgcn_s_barrier();
    COMPUTE_T(cb);

    #undef STAGE_T
    #undef COMPUTE_T

    int rbase = quad * 4;
    #pragma unroll
    for (int i = 0; i < MREP; ++i) {
        #pragma unroll
        for (int n = 0; n < 2; ++n) {
            int gc = n0 + wcol + n * 16 + l15;
            float bv = bias[gc];
            int gr = m0 + wrow + i * 16 + rbase;
            #pragma unroll
            for (int reg = 0; reg < 4; ++reg) {
                if constexpr (EPI == 0) {
                    ((ushort*)Cout)[(size_t)(gr + reg) * N + gc] =
                        f2bf(fast_gelu(acc[i][n][reg] + bv));
                } else if constexpr (EPI == 1) {
                    ((float*)Cout)[(size_t)(gr + reg) * N + gc] = acc[i][n][reg] + bv;
                } else {
                    float* xp = (float*)Cout + (size_t)(gr + reg) * N + gc;
                    *xp = *xp + acc[i][n][reg] + bv;
                }
            }
        }
    }
}

// ---------------- CLS-only final layer: fused LN + MLP-up (per-block redundant LN) ----------
// Each of the 32 blocks LNs the 16 CLS rows (32KB L2-hot) into padded LDS [16][520]
// (banks: 4*l15+4*quad mod 32 -> 2 lanes/bank, free), then the verified gemm1_cls frag path.
#define HCPAD 520
__global__ __launch_bounds__(256) void lngemm1_cls(const float* __restrict__ x,
                                                   const float* __restrict__ g,
                                                   const float* __restrict__ bb,
                                                   const ushort* __restrict__ W1t,
                                                   const float* __restrict__ b1,
                                                   ushort* __restrict__ uc) {
    __shared__ ushort h2l[16 * HCPAD];   // 16.6 KB
    int tid = threadIdx.x;
    int lane = tid & 63;
    int w = __builtin_amdgcn_readfirstlane(tid >> 6);   // 0..3
    int quad = lane >> 4, l15 = lane & 15;

    // LN of the 16 CLS rows (4 iters x 4 waves) — math identical to ln_kernel
    #pragma unroll
    for (int it = 0; it < 4; ++it) {
        int r = it * 4 + w;
        const float* xr = x + (size_t)r * T * D + lane * 8;
        float4 a0 = *(const float4*)xr;
        float4 a1 = *(const float4*)(xr + 4);
        float s = a0.x + a0.y + a0.z + a0.w + a1.x + a1.y + a1.z + a1.w;
        #pragma unroll
        for (int off = 1; off < 64; off <<= 1) s += __shfl_xor(s, off);
        float mean = s * (1.0f / (float)D);
        float d0 = a0.x - mean, d1 = a0.y - mean, d2 = a0.z - mean, d3 = a0.w - mean;
        float d4 = a1.x - mean, d5 = a1.y - mean, d6 = a1.z - mean, d7 = a1.w - mean;
        float sq = d0*d0 + d1*d1 + d2*d2 + d3*d3 + d4*d4 + d5*d5 + d6*d6 + d7*d7;
        #pragma unroll
        for (int off = 1; off < 64; off <<= 1) sq += __shfl_xor(sq, off);
        float rstd = rsqrtf(sq * (1.0f / (float)D) + EPS);
        const float* gp = g + lane * 8;
        const float* bp = bb + lane * 8;
        float4 g0 = *(const float4*)gp, g1 = *(const float4*)(gp + 4);
        float4 b0 = *(const float4*)bp, b1v = *(const float4*)(bp + 4);
        short8 o;
        o[0] = (short)f2bf(d0 * rstd * g0.x + b0.x);
        o[1] = (short)f2bf(d1 * rstd * g0.y + b0.y);
        o[2] = (short)f2bf(d2 * rstd * g0.z + b0.z);
        o[3] = (short)f2bf(d3 * rstd * g0.w + b0.w);
        o[4] = (short)f2bf(d4 * rstd * g1.x + b1v.x);
        o[5] = (short)f2bf(d5 * rstd * g1.y + b1v.y);
        o[6] = (short)f2bf(d6 * rstd * g1.z + b1v.z);
        o[7] = (short)f2bf(d7 * rstd * g1.w + b1v.w);
        *(short8*)(h2l + r * HCPAD + lane * 8) = o;
    }
    __syncthreads();

    int nb = blockIdx.x * 64 + w * 16;
    short8 af[16];
    #pragma unroll
    for (int ks = 0; ks < 16; ++ks)
        af[ks] = *(const short8*)&h2l[l15 * HCPAD + ks * 32 + quad * 8];

    const ushort* wrow = W1t + (size_t)(nb + l15) * D + quad * 8;
    floatx4 acc = (floatx4)0.f;
    #pragma unroll
    for (int ks = 0; ks < 16; ++ks) {
        short8 bf = *(const short8*)(wrow + ks * 32);
        acc = __builtin_amdgcn_mfma_f32_16x16x32_bf16(af[ks], bf, acc, 0, 0, 0);
    }
    float bv = b1[nb + l15];
    #pragma unroll
    for (int reg = 0; reg < 4; ++reg)
        uc[(size_t)(quad * 4 + reg) * MLPD + nb + l15] = f2bf(fast_gelu(acc[reg] + bv));
}

__global__ __launch_bounds__(256) void gemm2_cls(const ushort* __restrict__ uc,
                                                 const ushort* __restrict__ W2t,
                                                 const float* __restrict__ b2,
                                                 float* __restrict__ p0c) {
    __shared__ float red[4 * 256];
    int tid = threadIdx.x;
    int lane = tid & 63;
    int w = __builtin_amdgcn_readfirstlane(tid >> 6);
    int quad = lane >> 4, l15 = lane & 15;
    int nb = blockIdx.x * 16;

    const ushort* wrow = W2t + (size_t)(nb + l15) * MLPD + quad * 8;
    floatx4 acc = (floatx4)0.f;
    #pragma unroll
    for (int k8 = 0; k8 < 16; ++k8) {
        int ks = w * 16 + k8;
        short8 a2 = *(const short8*)&uc[(size_t)l15 * MLPD + ks * 32 + quad * 8];
        short8 bf = *(const short8*)(wrow + (size_t)ks * 32);
        acc = __builtin_amdgcn_mfma_f32_16x16x32_bf16(a2, bf, acc, 0, 0, 0);
    }
    #pragma unroll
    for (int reg = 0; reg < 4; ++reg)
        red[w * 256 + (quad * 4 + reg) * 16 + l15] = acc[reg];
    __syncthreads();
    int row = tid >> 4, col = tid & 15;
    float s = red[row * 16 + col] + red[256 + row * 16 + col]
            + red[512 + row * 16 + col] + red[768 + row * 16 + col];
    p0c[(size_t)row * D + nb + col] = s + b2[nb + col];
}

// ---------------- head: out[b] = sigmoid((x[b,0]+p0c[b]) . head_W + head_b) ----------------
__global__ void head_kernel(const float* __restrict__ x,
                            const float* __restrict__ p0c,
                            const float* __restrict__ hw,
                            const float* __restrict__ hb,
                            float* __restrict__ out) {
    int b = blockIdx.x;
    int tid = threadIdx.x; // 512
    float s = (x[(size_t)b * T * D + tid] + p0c[(size_t)b * D + tid]) * hw[tid];
    #pragma unroll
    for (int off = 32; off > 0; off >>= 1) s += __shfl_down(s, off, 64);
    __shared__ float red[8];
    if ((tid & 63) == 0) red[tid >> 6] = s;
    __syncthreads();
    if (tid == 0) {
        float t = 0.f;
        #pragma unroll
        for (int i = 0; i < 8; ++i) t += red[i];
        out[b] = 1.0f / (1.0f + __expf(-(t + hb[0])));
    }
}

extern "C" void kernel_launch(void* const* d_in, const int* in_sizes, int n_in,
                              void* d_out, int out_size, void* d_ws, size_t ws_size,
                              hipStream_t stream) {
    const float* src     = (const float*)d_in[0];
    const float* emb_W   = (const float*)d_in[1];
    const float* emb_b   = (const float*)d_in[2];
    const float* cls_tok = (const float*)d_in[3];
    const float* ln1_g   = (const float*)d_in[4];
    const float* ln1_b   = (const float*)d_in[5];
    const float* Wq      = (const float*)d_in[6];
    const float* bq      = (const float*)d_in[7];
    const float* Wk      = (const float*)d_in[8];
    const float* bk      = (const float*)d_in[9];
    const float* Wv      = (const float*)d_in[10];
    const float* bv      = (const float*)d_in[11];
    const float* ln2_g   = (const float*)d_in[12];
    const float* ln2_b   = (const float*)d_in[13];
    const float* W1      = (const float*)d_in[14];
    const float* b1      = (const float*)d_in[15];
    const float* W2      = (const float*)d_in[16];
    const float* b2      = (const float*)d_in[17];
    const float* head_W  = (const float*)d_in[18];
    const float* head_b  = (const float*)d_in[19];

    const size_t NTOK = (size_t)B * T;          // 8192
    char* wsb = (char*)d_ws;
    float*  x    = (float*)wsb;      wsb += NTOK * D * 4;
    ushort* hbuf = (ushort*)wsb;     wsb += NTOK * D * 2;
    ushort* q    = (ushort*)wsb;     wsb += NTOK * D * 2;
    ushort* k    = (ushort*)wsb;     wsb += NTOK * D * 2;
    ushort* vT   = (ushort*)wsb;     wsb += NTOK * D * 2;
    ushort* u    = (ushort*)wsb;     wsb += NTOK * MLPD * 2;
    ushort* W1t  = (ushort*)wsb;     wsb += (size_t)NB * D * MLPD * 2;
    ushort* W2t  = (ushort*)wsb;     wsb += (size_t)NB * D * MLPD * 2;
    ushort* WqT  = (ushort*)wsb;     wsb += (size_t)NB * H * DH * DH * 2;
    ushort* WkT  = (ushort*)wsb;     wsb += (size_t)NB * H * DH * DH * 2;
    ushort* WvT  = (ushort*)wsb;     wsb += (size_t)NB * H * DH * DH * 2;
    ushort* srcb = (ushort*)wsb;     wsb += NTOK * F * 2;
    ushort* embWt= (ushort*)wsb;     wsb += (size_t)F * D * 2;
    ushort* ucls = (ushort*)wsb;     wsb += (size_t)16 * MLPD * 2;
    float*  p0c  = (float*)wsb;      wsb += (size_t)16 * D * 4;

    // weight / input prep (every launch)
    wtrans_kernel<<<dim3(D / 32, MLPD / 32, NB), 256, 0, stream>>>(W1, W1t, D, MLPD);
    wtrans_kernel<<<dim3(MLPD / 32, D / 32, NB), 256, 0, stream>>>(W2, W2t, MLPD, D);
    wtransq_kernel<<<dim3(NB * H, 3), 256, 0, stream>>>(Wq, Wk, Wv, WqT, WkT, WvT);
    wtrans_kernel<<<dim3(F / 32, D / 32, 1), 256, 0, stream>>>(emb_W, embWt, F, D);
    castsrc_kernel<<<B * T, F, 0, stream>>>(src, srcb);

    embed_gemm<<<dim3(B * T / 64, D / 64), 256, 0, stream>>>(srcb, embWt, emb_b, cls_tok, x);

    for (int i = 0; i < NB; ++i) {
        lnqkv_kernel<<<B * T / 32, 256, 0, stream>>>(x,
            ln1_g + i * D, ln1_b + i * D,
            WqT + (size_t)i * H * DH * DH, bq + (size_t)i * H * DH,
            WkT + (size_t)i * H * DH * DH, bk + (size_t)i * H * DH,
            WvT + (size_t)i * H * DH * DH, bv + (size_t)i * H * DH,
            q, k, vT);
        if (i < NB - 1) {
            attn_kernel<<<dim3(B * H, T / 64), 256, 0, stream>>>(q, k, vT, x);
            ln_kernel<<<B * T / 4, 256, 0, stream>>>(x, ln2_g + i * D, ln2_b + i * D, hbuf);
            gemm1_8p<<<dim3((B * T / 256) * (MLPD / 256)), 512, 0, stream>>>(
                hbuf, W1t + (size_t)i * D * MLPD, b1 + (size_t)i * MLPD, u, MLPD, D);
            gemm_pipe<128, 2><<<dim3(B * T / 128, D / 128), 512, 0, stream>>>(
                u, W2t + (size_t)i * MLPD * D, b2 + (size_t)i * D, x, D, MLPD);
        } else {
            // final layer: only CLS rows matter downstream. Attend only q-tile 0, then
            // CLS-only {LN2+MLP-up fused, MLP-down} spread across CUs; head reads x+p0c.
            attn_kernel<<<dim3(B * H, 1), 256, 0, stream>>>(q, k, vT, x);
            lngemm1_cls<<<MLPD / 64, 256, 0, stream>>>(x,
                ln2_g + (size_t)i * D, ln2_b + (size_t)i * D,
                W1t + (size_t)i * D * MLPD, b1 + (size_t)i * MLPD, ucls);
            gemm2_cls<<<D / 16, 256, 0, stream>>>(ucls,
                W2t + (size_t)i * MLPD * D, b2 + (size_t)i * D, p0c);
            head_kernel<<<B, 512, 0, stream>>>(x, p0c, head_W, head_b, (float*)d_out);
        }
    }
}

// Round 11
// 748.826 us; speedup vs baseline: 1.0565x; 1.0046x over previous
//
#include <hip/hip_runtime.h>
#include <hip/hip_bf16.h>
#include <math.h>

#define B 16
#define S 511
#define F 128
#define D 512
#define H 8
#define NB 6
#define DH 64
#define MLPD 2048
#define T 512
#define EPS 1e-5f

typedef unsigned short ushort;
typedef __attribute__((ext_vector_type(8))) short short8;
typedef __attribute__((ext_vector_type(4))) float floatx4;

__device__ __forceinline__ ushort f2bf(float f) {
    union { float f; unsigned u; } cv; cv.f = f;
    unsigned r = (cv.u + 0x7fff + ((cv.u >> 16) & 1)) >> 16;  // RNE
    return (ushort)r;
}

// Branch-free erf (Abramowitz-Stegun 7.1.26, |err| <= 1.5e-7)
__device__ __forceinline__ float fast_gelu(float x) {
    float z = fabsf(x) * 0.70710678118f;
    float t = 1.0f / (1.0f + 0.3275911f * z);
    float p = ((((1.061405429f * t - 1.453152027f) * t + 1.421413741f) * t
               - 0.284496736f) * t + 0.254829592f) * t;
    float erfv = 1.0f - p * __expf(-z * z);
    erfv = copysignf(erfv, x);
    return 0.5f * x * (1.0f + erfv);
}

// ---------------- cast src -> bf16 A-matrix for embed GEMM (t=0 rows zeroed) ----------------
// Vectorized: float4 loads, ushort4 stores (was scalar 4B/lane).
__global__ __launch_bounds__(256) void castsrc_kernel(const float* __restrict__ src,
                                                      ushort* __restrict__ srcb) {
    int gid = blockIdx.x * 256 + threadIdx.x;   // B*T*F/4 = 262144 threads
    int row = gid >> 5;                         // 32 float4-chunks per row (F=128)
    int c4 = (gid & 31) * 4;
    int t = row & (T - 1), b = row >> 9;
    ushort4 o = {0, 0, 0, 0};
    if (t > 0) {
        float4 v = *(const float4*)&src[((size_t)b * S + (t - 1)) * F + c4];
        o.x = f2bf(v.x); o.y = f2bf(v.y); o.z = f2bf(v.z); o.w = f2bf(v.w);
    }
    *(ushort4*)&srcb[(size_t)row * F + c4] = o;
}

// ---------------- generic transpose+cast: W [mat,K,N] fp32 -> Wt [mat,N,K] bf16 ----------------
__global__ void wtrans_kernel(const float* __restrict__ W,
                              ushort* __restrict__ Wt,
                              int K, int N) {
    int kb = blockIdx.x * 32, nb = blockIdx.y * 32, mat = blockIdx.z;
    __shared__ float tile[32][33];
    int tid = threadIdx.x; // 256
    int c = tid & 31, r0 = tid >> 5;
    const float* Wm = W + (size_t)mat * K * N;
    ushort* Wtm = Wt + (size_t)mat * K * N;
    #pragma unroll
    for (int l = 0; l < 4; ++l) {
        int r = r0 + l * 8;
        tile[r][c] = Wm[(size_t)(kb + r) * N + nb + c];
    }
    __syncthreads();
    #pragma unroll
    for (int l = 0; l < 4; ++l) {
        int r = r0 + l * 8;
        Wtm[(size_t)(nb + r) * K + kb + c] = f2bf(tile[c][r]);
    }
}

// ---------------- qkv weight transpose+cast ----------------
__global__ void wtransq_kernel(const float* __restrict__ Wq, const float* __restrict__ Wk,
                               const float* __restrict__ Wv,
                               ushort* __restrict__ WqT, ushort* __restrict__ WkT,
                               ushort* __restrict__ WvT) {
    int mat = blockIdx.x;          // 0..NB*H-1
    int which = blockIdx.y;        // 0,1,2
    const float* W = (which == 0 ? Wq : which == 1 ? Wk : Wv) + (size_t)mat * 4096;
    ushort* O = (which == 0 ? WqT : which == 1 ? WkT : WvT) + (size_t)mat * 4096;
    __shared__ float t[64][65];
    int tid = threadIdx.x;  // 256
    int r0 = tid >> 6, c = tid & 63;
    #pragma unroll
    for (int l = 0; l < 16; ++l) {
        int row = r0 * 16 + l;
        t[row][c] = W[row * 64 + c];
    }
    __syncthreads();
    #pragma unroll
    for (int l = 0; l < 16; ++l) {
        int row = r0 * 16 + l;
        O[row * 64 + c] = f2bf(t[c][row]);
    }
}

// ---------------- async global->LDS helper ----------------
__device__ __forceinline__ void gload_lds16(const ushort* g, ushort* l) {
    __builtin_amdgcn_global_load_lds((const __attribute__((address_space(1))) unsigned int*)g,
                                     (__attribute__((address_space(3))) unsigned int*)l,
                                     16, 0, 0);
}

#define S_WAITCNT_VM(N) asm volatile("s_waitcnt vmcnt(" #N ")" ::: "memory")
#define S_WAITCNT_LGKM0 asm volatile("s_waitcnt lgkmcnt(0)" ::: "memory")
#define S_WAITCNT_LGKM8 asm volatile("s_waitcnt lgkmcnt(8)" ::: "memory")

// ---------------- embed GEMM: x = concat(cls, srcb@embWt^T)+emb_b+pe, fp32 out ----------------
__global__ __launch_bounds__(256) void embed_gemm(const ushort* __restrict__ A,
                                                  const ushort* __restrict__ Bt,
                                                  const float* __restrict__ emb_b,
                                                  const float* __restrict__ cls_tok,
                                                  float* __restrict__ x) {
    __shared__ ushort As[64 * 32];
    __shared__ ushort Bs[64 * 32];
    int tid = threadIdx.x;
    int lane = tid & 63;
    int w = __builtin_amdgcn_readfirstlane(tid >> 6);
    int quad = lane >> 4, l15 = lane & 15;
    int wr = (w >> 1) * 32, wc = (w & 1) * 32;
    int m0 = blockIdx.x * 64, n0 = blockIdx.y * 64;

    floatx4 acc[2][2];
    #pragma unroll
    for (int i = 0; i < 2; ++i)
        #pragma unroll
        for (int j = 0; j < 2; ++j) acc[i][j] = (floatx4)0.f;

    int lrow = lane >> 2;
    int lk = (lane & 3) * 8;
    const ushort* Ag = A + (size_t)(m0 + 16 * w + lrow) * F + lk;
    const ushort* Bg = Bt + (size_t)(n0 + 16 * w + lrow) * F + lk;
    ushort* AsW = &As[16 * w * 32];
    ushort* BsW = &Bs[16 * w * 32];
    int fa = l15 * 32 + quad * 8;

    for (int kt = 0; kt < F; kt += 32) {
        gload_lds16(Ag + kt, AsW);
        gload_lds16(Bg + kt, BsW);
        __syncthreads();
        short8 af[2], bf[2];
        #pragma unroll
        for (int i = 0; i < 2; ++i) af[i] = *(const short8*)&As[(wr + 16 * i) * 32 + fa];
        #pragma unroll
        for (int j = 0; j < 2; ++j) bf[j] = *(const short8*)&Bs[(wc + 16 * j) * 32 + fa];
        #pragma unroll
        for (int i = 0; i < 2; ++i)
            #pragma unroll
            for (int j = 0; j < 2; ++j)
                acc[i][j] = __builtin_amdgcn_mfma_f32_16x16x32_bf16(af[i], bf[j], acc[i][j], 0, 0, 0);
        __syncthreads();
    }

    const float LOG1E4 = 9.210340371976184f;
    int rbase = (lane >> 4) * 4;
    int cidx = lane & 15;
    #pragma unroll
    for (int j = 0; j < 2; ++j) {
        int gc = n0 + wc + 16 * j + cidx;
        float je = (float)(gc & ~1);
        float freq = expf(-(je / (float)D) * LOG1E4);
        float ebv = emb_b[gc];
        float clsv = cls_tok[gc];
        bool odd = (gc & 1);
        #pragma unroll
        for (int i = 0; i < 2; ++i) {
            int gr = m0 + wr + 16 * i + rbase;
            #pragma unroll
            for (int reg = 0; reg < 4; ++reg) {
                int row = gr + reg;
                int t = row & (T - 1);
                float ang = (float)t * freq;
                float pe = odd ? cosf(ang) : sinf(ang);
                float val = (t == 0) ? (clsv + pe) : (acc[i][j][reg] + ebv + pe);
                x[(size_t)row * D + gc] = val;
            }
        }
    }
}

// ---------------- layernorm -> bf16: one wave per row, shuffle-only ----------------
__global__ __launch_bounds__(256) void ln_kernel(const float* __restrict__ xin,
                                                 const float* __restrict__ g,
                                                 const float* __restrict__ bb,
                                                 ushort* __restrict__ out) {
    int lane = threadIdx.x & 63;
    int row = blockIdx.x * 4 + (threadIdx.x >> 6);
    const float* xr = xin + (size_t)row * D + lane * 8;
    float4 a0 = *(const float4*)xr;
    float4 a1 = *(const float4*)(xr + 4);
    float s = a0.x + a0.y + a0.z + a0.w + a1.x + a1.y + a1.z + a1.w;
    #pragma unroll
    for (int off = 1; off < 64; off <<= 1) s += __shfl_xor(s, off);
    float mean = s * (1.0f / (float)D);
    float d0 = a0.x - mean, d1 = a0.y - mean, d2 = a0.z - mean, d3 = a0.w - mean;
    float d4 = a1.x - mean, d5 = a1.y - mean, d6 = a1.z - mean, d7 = a1.w - mean;
    float sq = d0*d0 + d1*d1 + d2*d2 + d3*d3 + d4*d4 + d5*d5 + d6*d6 + d7*d7;
    #pragma unroll
    for (int off = 1; off < 64; off <<= 1) sq += __shfl_xor(sq, off);
    float rstd = rsqrtf(sq * (1.0f / (float)D) + EPS);
    const float* gp = g + lane * 8;
    const float* bp = bb + lane * 8;
    float4 g0 = *(const float4*)gp, g1 = *(const float4*)(gp + 4);
    float4 b0 = *(const float4*)bp, b1 = *(const float4*)(bp + 4);
    short8 o;
    o[0] = (short)f2bf(d0 * rstd * g0.x + b0.x);
    o[1] = (short)f2bf(d1 * rstd * g0.y + b0.y);
    o[2] = (short)f2bf(d2 * rstd * g0.z + b0.z);
    o[3] = (short)f2bf(d3 * rstd * g0.w + b0.w);
    o[4] = (short)f2bf(d4 * rstd * g1.x + b1.x);
    o[5] = (short)f2bf(d5 * rstd * g1.y + b1.y);
    o[6] = (short)f2bf(d6 * rstd * g1.z + b1.z);
    o[7] = (short)f2bf(d7 * rstd * g1.w + b1.w);
    *(short8*)(out + (size_t)row * D + lane * 8) = o;
}

// ---------------- fused LN1 + QKV: 32-row block; LN into padded LDS, then per-head MFMA ------
#define LQPAD 520
__global__ __launch_bounds__(256) void lnqkv_kernel(
        const float* __restrict__ x,
        const float* __restrict__ g, const float* __restrict__ bb,
        const ushort* __restrict__ WqT, const float* __restrict__ bq,
        const ushort* __restrict__ WkT, const float* __restrict__ bk,
        const ushort* __restrict__ WvT, const float* __restrict__ bv,
        ushort* __restrict__ qo, ushort* __restrict__ ko, ushort* __restrict__ vTo) {
    __shared__ ushort hl[32 * LQPAD];   // 33.3 KB
    int tid = threadIdx.x;
    int lane = tid & 63;
    int w = __builtin_amdgcn_readfirstlane(tid >> 6);   // 0..3
    int quad = lane >> 4, l15 = lane & 15;
    int m0 = blockIdx.x * 32;

    for (int it = 0; it < 8; ++it) {
        int lr = it * 4 + w;
        const float* xr = x + (size_t)(m0 + lr) * D + lane * 8;
        float4 a0 = *(const float4*)xr;
        float4 a1 = *(const float4*)(xr + 4);
        float s = a0.x + a0.y + a0.z + a0.w + a1.x + a1.y + a1.z + a1.w;
        #pragma unroll
        for (int off = 1; off < 64; off <<= 1) s += __shfl_xor(s, off);
        float mean = s * (1.0f / (float)D);
        float d0 = a0.x - mean, d1 = a0.y - mean, d2 = a0.z - mean, d3 = a0.w - mean;
        float d4 = a1.x - mean, d5 = a1.y - mean, d6 = a1.z - mean, d7 = a1.w - mean;
        float sq = d0*d0 + d1*d1 + d2*d2 + d3*d3 + d4*d4 + d5*d5 + d6*d6 + d7*d7;
        #pragma unroll
        for (int off = 1; off < 64; off <<= 1) sq += __shfl_xor(sq, off);
        float rstd = rsqrtf(sq * (1.0f / (float)D) + EPS);
        const float* gp = g + lane * 8;
        const float* bp = bb + lane * 8;
        float4 g0 = *(const float4*)gp, g1 = *(const float4*)(gp + 4);
        float4 b0 = *(const float4*)bp, b1v = *(const float4*)(bp + 4);
        short8 o;
        o[0] = (short)f2bf(d0 * rstd * g0.x + b0.x);
        o[1] = (short)f2bf(d1 * rstd * g0.y + b0.y);
        o[2] = (short)f2bf(d2 * rstd * g0.z + b0.z);
        o[3] = (short)f2bf(d3 * rstd * g0.w + b0.w);
        o[4] = (short)f2bf(d4 * rstd * g1.x + b1v.x);
        o[5] = (short)f2bf(d5 * rstd * g1.y + b1v.y);
        o[6] = (short)f2bf(d6 * rstd * g1.z + b1v.z);
        o[7] = (short)f2bf(d7 * rstd * g1.w + b1v.w);
        *(short8*)(hl + lr * LQPAD + lane * 8) = o;
    }
    __syncthreads();

    int bb_ = m0 >> 9;
    #pragma unroll
    for (int hp = 0; hp < 2; ++hp) {
        int hh = w * 2 + hp;
        short8 af[2][2];
        #pragma unroll
        for (int mt = 0; mt < 2; ++mt)
            #pragma unroll
            for (int ks = 0; ks < 2; ++ks)
                af[mt][ks] = *(const short8*)&hl[(mt * 16 + l15) * LQPAD + hh * DH + ks * 32 + quad * 8];

        floatx4 acc[3][2][4];
        #pragma unroll
        for (int xo = 0; xo < 3; ++xo)
            #pragma unroll
            for (int mt = 0; mt < 2; ++mt)
                #pragma unroll
                for (int nt = 0; nt < 4; ++nt) acc[xo][mt][nt] = (floatx4)0.f;

        #pragma unroll
        for (int xo = 0; xo < 3; ++xo) {
            const ushort* WT = (xo == 0 ? WqT : xo == 1 ? WkT : WvT) + (size_t)hh * 4096;
            #pragma unroll
            for (int nt = 0; nt < 4; ++nt) {
                const ushort* wb = WT + (size_t)(nt * 16 + l15) * 64 + quad * 8;
                short8 bf0 = *(const short8*)(wb);
                short8 bf1 = *(const short8*)(wb + 32);
                #pragma unroll
                for (int mt = 0; mt < 2; ++mt) {
                    acc[xo][mt][nt] = __builtin_amdgcn_mfma_f32_16x16x32_bf16(af[mt][0], bf0, acc[xo][mt][nt], 0, 0, 0);
                    acc[xo][mt][nt] = __builtin_amdgcn_mfma_f32_16x16x32_bf16(af[mt][1], bf1, acc[xo][mt][nt], 0, 0, 0);
                }
            }
        }

        int bh = bb_ * H + hh;
        #pragma unroll
        for (int mt = 0; mt < 2; ++mt) {
            int trow = m0 + mt * 16 + quad * 4;
            int tt = trow & (T - 1);
            #pragma unroll
            for (int nt = 0; nt < 4; ++nt) {
                int col = nt * 16 + l15;
                float bqv = bq[hh * DH + col];
                float bkv = bk[hh * DH + col];
                float bvv = bv[hh * DH + col];
                #pragma unroll
                for (int reg = 0; reg < 4; ++reg) {
                    qo[((size_t)bh * T + tt + reg) * DH + col] = f2bf(acc[0][mt][nt][reg] + bqv);
                    ko[((size_t)bh * T + tt + reg) * DH + col] = f2bf(acc[1][mt][nt][reg] + bkv);
                    vTo[((size_t)bh * DH + col) * T + tt + reg] = f2bf(acc[2][mt][nt][reg] + bvv);
                }
            }
        }
    }
}

// ---------------- MFMA flash attention: Q-tile 128 rows, 8 waves (waves 0-3 stage K, 4-7 V) --
// Halves block count (512 vs 1024): K/V fetched once per 128 q-rows, barrier cost halved.
// Per-wave fragment math, softmax (scalar f2bf), P layout identical to r8-verified version.
#define PSTRIDE 88
__global__ __launch_bounds__(512) void attn_kernel(const ushort* __restrict__ q,
                                                   const ushort* __restrict__ k,
                                                   const ushort* __restrict__ vT,
                                                   float* __restrict__ x) {
    int bh = blockIdx.x;
    int qt = blockIdx.y;                                // 0..T/128-1
    int b = bh >> 3, hh = bh & 7;
    int tid = threadIdx.x;
    int lane = tid & 63;
    int w = __builtin_amdgcn_readfirstlane(tid >> 6);   // 0..7
    int quad = lane >> 4, l15 = lane & 15;

    __shared__ __align__(16) ushort smem[27648];        // K dbuf 16KB | V dbuf 16KB | P 8x2816B
    ushort* Pw = smem + 16384 + w * (16 * PSTRIDE);

    const ushort* qbase = q + ((size_t)bh * T + qt * 128 + w * 16 + l15) * DH + quad * 8;
    short8 Qf0 = *(const short8*)(qbase);
    short8 Qf1 = *(const short8*)(qbase + 32);

    const ushort* kbase = k + (size_t)bh * T * DH;
    const ushort* vbase = vT + (size_t)bh * DH * T;

    int srow = lane >> 2;
    int scol = (lane & 3) * 8;
    // waves 0-3 stage K rows w*16..w*16+15; waves 4-7 stage V rows (w-4)*16..
    int wk = w & 3;
    bool isK = (w < 4);
    const ushort* sg = isK ? (kbase + (size_t)(wk * 16 + srow) * DH + scol)
                           : (vbase + (size_t)(wk * 16 + srow) * T + scol);
    int sstep = isK ? (64 * DH) : 64;                   // per-kt advance (elements)
    ushort* ldsS = smem + (isK ? 0 : 8192) + wk * 16 * 32;

    float l_i[4] = {0.f, 0.f, 0.f, 0.f};
    floatx4 O[4];
    #pragma unroll
    for (int j = 0; j < 4; ++j) O[j] = (floatx4)0.f;

    gload_lds16(sg, ldsS);
    gload_lds16(sg + 32, ldsS + 2048);
    __syncthreads();

    for (int kt = 0; kt < T / 64; ++kt) {
        int cur = kt & 1;
        if (kt < T / 64 - 1) {
            int nb = cur ^ 1;
            const ushort* sgn = sg + (size_t)(kt + 1) * sstep;
            gload_lds16(sgn, ldsS + nb * 4096);
            gload_lds16(sgn + 32, ldsS + nb * 4096 + 2048);
        }
        const ushort* Kc = smem + cur * 4096;
        const ushort* Vc = smem + 8192 + cur * 4096;

        floatx4 sc[4];
        __builtin_amdgcn_s_setprio(1);
        #pragma unroll
        for (int j = 0; j < 4; ++j) {
            int ro = (j * 16 + l15) * 32 + quad * 8;
            short8 kf0 = *(const short8*)&Kc[ro];
            short8 kf1 = *(const short8*)&Kc[2048 + ro];
            floatx4 s4 = (floatx4)0.f;
            s4 = __builtin_amdgcn_mfma_f32_16x16x32_bf16(Qf0, kf0, s4, 0, 0, 0);
            s4 = __builtin_amdgcn_mfma_f32_16x16x32_bf16(Qf1, kf1, s4, 0, 0, 0);
            sc[j] = s4;
        }
        __builtin_amdgcn_s_setprio(0);
        #pragma unroll
        for (int j = 0; j < 4; ++j) {
            #pragma unroll
            for (int r = 0; r < 4; ++r) {
                float p = __expf(sc[j][r] * 0.125f);
                l_i[r] += p;
                Pw[(quad * 4 + r) * PSTRIDE + j * 16 + l15] = f2bf(p);
            }
        }

        short8 af0 = *(const short8*)&Pw[l15 * PSTRIDE + quad * 8];
        short8 af1 = *(const short8*)&Pw[l15 * PSTRIDE + 32 + quad * 8];
        __builtin_amdgcn_s_setprio(1);
        #pragma unroll
        for (int j = 0; j < 4; ++j) {
            int ro = (j * 16 + l15) * 32 + quad * 8;
            short8 vf0 = *(const short8*)&Vc[ro];
            short8 vf1 = *(const short8*)&Vc[2048 + ro];
            O[j] = __builtin_amdgcn_mfma_f32_16x16x32_bf16(af0, vf0, O[j], 0, 0, 0);
            O[j] = __builtin_amdgcn_mfma_f32_16x16x32_bf16(af1, vf1, O[j], 0, 0, 0);
        }
        __builtin_amdgcn_s_setprio(0);
        __syncthreads();
    }

    #pragma unroll
    for (int r = 0; r < 4; ++r) {
        l_i[r] += __shfl_xor(l_i[r], 1);
        l_i[r] += __shfl_xor(l_i[r], 2);
        l_i[r] += __shfl_xor(l_i[r], 4);
        l_i[r] += __shfl_xor(l_i[r], 8);
    }

    float* Ow = (float*)smem + w * 16 * 68;   // 8 waves x 4352B = 34.8KB < 55.3KB (reuse)
    #pragma unroll
    for (int r = 0; r < 4; ++r) {
        float rl = 1.0f / l_i[r];
        #pragma unroll
        for (int j = 0; j < 4; ++j)
            Ow[(quad * 4 + r) * 68 + j * 16 + l15] = O[j][r] * rl;
    }
    __syncthreads();
    int r4 = lane >> 4;
    int c16 = lane & 15;
    #pragma unroll
    for (int i = 0; i < 4; ++i) {
        int lrow = i * 4 + r4;
        float4 o = *(const float4*)&Ow[lrow * 68 + c16 * 4];
        int grow = qt * 128 + w * 16 + lrow;
        float* xp = &x[((size_t)(b * T) + grow) * D + hh * DH + c16 * 4];
        float4 xv = *(const float4*)xp;
        xv.x += o.x; xv.y += o.y; xv.z += o.z; xv.w += o.w;
        *(float4*)xp = xv;
    }
}

// ---------------- gemm1: m201-style 256x256 8-phase, BK=64, 2 K-tiles/iter, counted vmcnt ----
// (r8-verified; ledger in r8 commit message)
__global__ __launch_bounds__(512, 1) void gemm1_8p(const ushort* __restrict__ A,
                                                   const ushort* __restrict__ Bt,
                                                   const float* __restrict__ bias,
                                                   ushort* __restrict__ C,
                                                   int N, int K) {
    constexpr int BUF = 32768;
    constexpr int BOFS = 16384;
    __shared__ ushort lds[2 * BUF];

    int tid = threadIdx.x;
    int lane = tid & 63;
    int w = __builtin_amdgcn_readfirstlane(tid >> 6);
    int quad = lane >> 4, l15 = lane & 15;
    int wm = w >> 2, wn = w & 3;
    int wmr = wm * 128, wnr = wn * 64;

    int nwg = gridDim.x;
    int id = blockIdx.x;
    int idx = (id & 7) * (nwg >> 3) + (id >> 3);
    int NTg = N >> 8;
    int mt = idx / NTg, nt = idx - mt * NTg;
    int m0 = mt * 256, n0 = nt * 256;

    int strow = tid >> 3;
    int ssw = ((tid & 7) ^ (strow & 7)) * 8;
    const ushort* Ag = A + (size_t)(m0 + strow) * K + ssw;
    const ushort* Bg = Bt + (size_t)(n0 + strow) * K + ssw;
    int wdst = w << 9;

    int sx0 = (quad ^ (l15 & 7)) * 8;
    int sx1 = ((4 + quad) ^ (l15 & 7)) * 8;

    floatx4 acc[8][4];
    #pragma unroll
    for (int i = 0; i < 8; ++i)
        #pragma unroll
        for (int n = 0; n < 4; ++n) acc[i][n] = (floatx4)0.f;

    short8 a[4][2], b[4][2];

    #define STG_AH(h, t, bp) do {                                                         \
        gload_lds16(Ag + (size_t)((h) * 128) * K + (size_t)(t) * 64,                      \
                    (bp) + ((h) * 128) * 64 + wdst);                                      \
        gload_lds16(Ag + (size_t)((h) * 128 + 64) * K + (size_t)(t) * 64,                 \
                    (bp) + ((h) * 128 + 64) * 64 + wdst);                                 \
    } while (0)
    #define STG_BH(h, t, bp) do {                                                         \
        gload_lds16(Bg + (size_t)((h) * 128) * K + (size_t)(t) * 64,                      \
                    (bp) + BOFS + ((h) * 128) * 64 + wdst);                                \
        gload_lds16(Bg + (size_t)((h) * 128 + 64) * K + (size_t)(t) * 64,                 \
                    (bp) + BOFS + ((h) * 128 + 64) * 64 + wdst);                           \
    } while (0)

    #define RD_A03(bp) do { _Pragma("unroll")                                             \
        for (int ks = 0; ks < 2; ++ks) { int sx = ks ? sx1 : sx0;                         \
            _Pragma("unroll")                                                             \
            for (int i = 0; i < 4; ++i)                                                   \
                a[i][ks] = *(const short8*)&(bp)[(wmr + i * 16 + l15) * 64 + sx]; } } while (0)
    #define RD_A47(bp) do { _Pragma("unroll")                                             \
        for (int ks = 0; ks < 2; ++ks) { int sx = ks ? sx1 : sx0;                         \
            _Pragma("unroll")                                                             \
            for (int i = 0; i < 4; ++i)                                                   \
                a[i][ks] = *(const short8*)&(bp)[(wmr + (4 + i) * 16 + l15) * 64 + sx]; } } while (0)
    #define RD_B01(bp) do { _Pragma("unroll")                                             \
        for (int ks = 0; ks < 2; ++ks) { int sx = ks ? sx1 : sx0;                         \
            _Pragma("unroll")                                                             \
            for (int n = 0; n < 2; ++n)                                                   \
                b[n][ks] = *(const short8*)&(bp)[BOFS + (wnr + n * 16 + l15) * 64 + sx]; } } while (0)
    #define RD_B23(bp) do { _Pragma("unroll")                                             \
        for (int ks = 0; ks < 2; ++ks) { int sx = ks ? sx1 : sx0;                         \
            _Pragma("unroll")                                                             \
            for (int n = 0; n < 2; ++n)                                                   \
                b[2 + n][ks] = *(const short8*)&(bp)[BOFS + (wnr + (2 + n) * 16 + l15) * 64 + sx]; } } while (0)

    #define MFQ(mb, nb2) do { _Pragma("unroll")                                           \
        for (int ks = 0; ks < 2; ++ks)                                                    \
            _Pragma("unroll")                                                             \
            for (int i = 0; i < 4; ++i)                                                   \
                _Pragma("unroll")                                                         \
                for (int n = 0; n < 2; ++n)                                               \
                    acc[(mb) + i][(nb2) + n] = __builtin_amdgcn_mfma_f32_16x16x32_bf16(   \
                        a[i][ks], b[(nb2) + n][ks], acc[(mb) + i][(nb2) + n], 0, 0, 0); } while (0)

    #define BAR __builtin_amdgcn_s_barrier()
    #define PRIO_MFQ(mb, nb2) do { __builtin_amdgcn_s_setprio(1); MFQ(mb, nb2);           \
                                   __builtin_amdgcn_s_setprio(0); } while (0)

    ushort* buf0 = lds;
    ushort* buf1 = lds + BUF;

    STG_AH(0, 0, buf0); STG_AH(1, 0, buf0); STG_BH(0, 0, buf0); STG_BH(1, 0, buf0);
    STG_BH(0, 1, buf1); STG_BH(1, 1, buf1); STG_AH(0, 1, buf1);
    S_WAITCNT_VM(6);
    BAR;

    int NITER = K >> 7;
    int NT = K >> 6;
    for (int it = 0; it < NITER; ++it) {
        int t2 = 2 * it + 2, t3 = 2 * it + 3;
        bool s2 = (t2 < NT);
        RD_A03(buf0); RD_B01(buf0);
        STG_AH(1, 2 * it + 1, buf1);
        S_WAITCNT_LGKM8;
        BAR; S_WAITCNT_LGKM0; PRIO_MFQ(0, 0); BAR;
        RD_B23(buf0);
        BAR; S_WAITCNT_LGKM0; PRIO_MFQ(0, 2); BAR;
        RD_A47(buf0);
        if (s2) { STG_BH(0, t2, buf0); STG_BH(1, t2, buf0); }
        BAR; S_WAITCNT_LGKM0; PRIO_MFQ(4, 2); BAR;
        if (s2) { STG_AH(0, t2, buf0); S_WAITCNT_VM(6); } else { S_WAITCNT_VM(0); }
        BAR; PRIO_MFQ(4, 0); BAR;
        RD_A03(buf1); RD_B01(buf1);
        if (s2) STG_AH(1, t2, buf0);
        S_WAITCNT_LGKM8;
        BAR; S_WAITCNT_LGKM0; PRIO_MFQ(0, 0); BAR;
        RD_B23(buf1);
        BAR; S_WAITCNT_LGKM0; PRIO_MFQ(0, 2); BAR;
        RD_A47(buf1);
        if (s2) { STG_BH(0, t3, buf1); STG_BH(1, t3, buf1); }
        BAR; S_WAITCNT_LGKM0; PRIO_MFQ(4, 2); BAR;
        if (s2) { STG_AH(0, t3, buf1); S_WAITCNT_VM(6); }
        BAR; PRIO_MFQ(4, 0); BAR;
    }

    #undef STG_AH
    #undef STG_BH
    #undef RD_A03
    #undef RD_A47
    #undef RD_B01
    #undef RD_B23
    #undef MFQ
    #undef BAR
    #undef PRIO_MFQ

    int rbase = quad * 4;
    #pragma unroll
    for (int i = 0; i < 8; ++i) {
        #pragma unroll
        for (int n = 0; n < 4; ++n) {
            int gc = n0 + wnr + n * 16 + l15;
            float bv = bias[gc];
            int gr = m0 + wmr + i * 16 + rbase;
            #pragma unroll
            for (int reg = 0; reg < 4; ++reg) {
                C[(size_t)(gr + reg) * N + gc] = f2bf(fast_gelu(acc[i][n][reg] + bv));
            }
        }
    }
}

// ---------------- pipelined MFMA GEMM (gemm2, r1 bench-best): 3-buffer LDS, distance 2 ------
// EPI 2: C(fp32) += acc+bias (fused residual add).
template<int BM, int EPI>
__global__ __launch_bounds__(512) void gemm_pipe(const ushort* __restrict__ A,
                                                 const ushort* __restrict__ Bt,
                                                 const float* __restrict__ bias,
                                                 void* __restrict__ Cout,
                                                 int N, int K) {
    constexpr int BN = 128;
    constexpr int BK = 64;
    constexpr int MREP = BM / 32;
    constexpr int AJ = BM / 64;
    constexpr int TILE = (BM + BN) * BK;
    __shared__ ushort lds[3 * TILE];

    int tid = threadIdx.x;
    int lane = tid & 63;
    int w = __builtin_amdgcn_readfirstlane(tid >> 6);
    int quad = lane >> 4, l15 = lane & 15;
    int wrow = (w >> 2) * (BM / 2);
    int wcol = (w & 3) * 32;
    int m0 = blockIdx.x * BM, n0 = blockIdx.y * BN;

    int lrow8 = lane >> 3;
    int lslot = lane & 7;
    int scol = (lslot ^ lrow8) * 8;
    const ushort* Asrc = A + (size_t)(m0 + w * 8 + lrow8) * K + scol;
    const ushort* Bsrc = Bt + (size_t)(n0 + w * 8 + lrow8) * K + scol;
    ushort* ldsA0 = lds + (w * 8) * BK;
    ushort* ldsB0 = lds + BM * BK + (w * 8) * BK;

    int sx0 = ((quad) ^ (l15 & 7)) * 8;
    int sx1 = ((4 + quad) ^ (l15 & 7)) * 8;

    floatx4 acc[MREP][2];
    #pragma unroll
    for (int i = 0; i < MREP; ++i) {
        acc[i][0] = (floatx4)0.f;
        acc[i][1] = (floatx4)0.f;
    }

    #define STAGE_T(t, buf) do {                                                   \
        const ushort* ap_ = Asrc + (size_t)(t) * BK;                               \
        const ushort* bp_ = Bsrc + (size_t)(t) * BK;                               \
        ushort* la_ = ldsA0 + (buf) * TILE;                                        \
        ushort* lb_ = ldsB0 + (buf) * TILE;                                        \
        _Pragma("unroll")                                                          \
        for (int j = 0; j < AJ; ++j)                                               \
            gload_lds16(ap_ + (size_t)j * 64 * K, la_ + j * 64 * BK);              \
        _Pragma("unroll")                                                          \
        for (int j = 0; j < 2; ++j)                                                \
            gload_lds16(bp_ + (size_t)j * 64 * K, lb_ + j * 64 * BK);              \
    } while (0)

    #define COMPUTE_T(buf) do {                                                    \
        const ushort* Ab_ = lds + (buf) * TILE;                                    \
        const ushort* Bb_ = Ab_ + BM * BK;                                         \
        _Pragma("unroll")                                                          \
        for (int ks = 0; ks < 2; ++ks) {                                           \
            int sx_ = ks ? sx1 : sx0;                                              \
            short8 bfr0 = *(const short8*)&Bb_[(wcol + l15) * BK + sx_];           \
            short8 bfr1 = *(const short8*)&Bb_[(wcol + 16 + l15) * BK + sx_];      \
            _Pragma("unroll")                                                      \
            for (int i = 0; i < MREP; ++i) {                                       \
                short8 af_ = *(const short8*)&Ab_[(wrow + i * 16 + l15) * BK + sx_]; \
                acc[i][0] = __builtin_amdgcn_mfma_f32_16x16x32_bf16(af_, bfr0, acc[i][0], 0, 0, 0); \
                acc[i][1] = __builtin_amdgcn_mfma_f32_16x16x32_bf16(af_, bfr1, acc[i][1], 0, 0, 0); \
            }                                                                      \
        }                                                                          \
    } while (0)

    STAGE_T(0, 0);
    STAGE_T(1, 1);

    int NT = K / BK;
    int cb = 0, nbuf = 2;
    for (int t = 0; t < NT - 2; ++t) {
        STAGE_T(t + 2, nbuf);
        if constexpr (AJ == 4) { S_WAITCNT_VM(12); } else { S_WAITCNT_VM(8); }
        __builtin_amdgcn_s_barrier();
        __builtin_amdgcn_s_setprio(1);
        COMPUTE_T(cb);
        __builtin_amdgcn_s_setprio(0);
        asm volatile("s_waitcnt lgkmcnt(0)" ::: "memory");
        __builtin_amdgcn_s_barrier();
        cb = (cb == 2) ? 0 : cb + 1;
        nbuf = (nbuf == 2) ? 0 : nbuf + 1;
    }
    if constexpr (AJ == 4) { S_WAITCNT_VM(6); } else { S_WAITCNT_VM(4); }
    __builtin_amdgcn_s_barrier();
    __builtin_amdgcn_s_setprio(1);
    COMPUTE_T(cb);
    __builtin_amdgcn_s_setprio(0);
    asm volatile("s_waitcnt lgkmcnt(0)" ::: "memory");
    __builtin_amdgcn_s_barrier();
    cb = (cb == 2) ? 0 : cb + 1;
    S_WAITCNT_VM(0);
    __builtin_amdgcn_s_barrier();
    COMPUTE_T(cb);

    #undef STAGE_T
    #undef COMPUTE_T

    int rbase = quad * 4;
    #pragma unroll
    for (int i = 0; i < MREP; ++i) {
        #pragma unroll
        for (int n = 0; n < 2; ++n) {
            int gc = n0 + wcol + n * 16 + l15;
            float bv = bias[gc];
            int gr = m0 + wrow + i * 16 + rbase;
            #pragma unroll
            for (int reg = 0; reg < 4; ++reg) {
                if constexpr (EPI == 0) {
                    ((ushort*)Cout)[(size_t)(gr + reg) * N + gc] =
                        f2bf(fast_gelu(acc[i][n][reg] + bv));
                } else if constexpr (EPI == 1) {
                    ((float*)Cout)[(size_t)(gr + reg) * N + gc] = acc[i][n][reg] + bv;
                } else {
                    float* xp = (float*)Cout + (size_t)(gr + reg) * N + gc;
                    *xp = *xp + acc[i][n][reg] + bv;
                }
            }
        }
    }
}

// ---------------- CLS-only final layer: fused LN + MLP-up (per-block redundant LN) ----------
#define HCPAD 520
__global__ __launch_bounds__(256) void lngemm1_cls(const float* __restrict__ x,
                                                   const float* __restrict__ g,
                                                   const float* __restrict__ bb,
                                                   const ushort* __restrict__ W1t,
                                                   const float* __restrict__ b1,
                                                   ushort* __restrict__ uc) {
    __shared__ ushort h2l[16 * HCPAD];   // 16.6 KB
    int tid = threadIdx.x;
    int lane = tid & 63;
    int w = __builtin_amdgcn_readfirstlane(tid >> 6);   // 0..3
    int quad = lane >> 4, l15 = lane & 15;

    #pragma unroll
    for (int it = 0; it < 4; ++it) {
        int r = it * 4 + w;
        const float* xr = x + (size_t)r * T * D + lane * 8;
        float4 a0 = *(const float4*)xr;
        float4 a1 = *(const float4*)(xr + 4);
        float s = a0.x + a0.y + a0.z + a0.w + a1.x + a1.y + a1.z + a1.w;
        #pragma unroll
        for (int off = 1; off < 64; off <<= 1) s += __shfl_xor(s, off);
        float mean = s * (1.0f / (float)D);
        float d0 = a0.x - mean, d1 = a0.y - mean, d2 = a0.z - mean, d3 = a0.w - mean;
        float d4 = a1.x - mean, d5 = a1.y - mean, d6 = a1.z - mean, d7 = a1.w - mean;
        float sq = d0*d0 + d1*d1 + d2*d2 + d3*d3 + d4*d4 + d5*d5 + d6*d6 + d7*d7;
        #pragma unroll
        for (int off = 1; off < 64; off <<= 1) sq += __shfl_xor(sq, off);
        float rstd = rsqrtf(sq * (1.0f / (float)D) + EPS);
        const float* gp = g + lane * 8;
        const float* bp = bb + lane * 8;
        float4 g0 = *(const float4*)gp, g1 = *(const float4*)(gp + 4);
        float4 b0 = *(const float4*)bp, b1v = *(const float4*)(bp + 4);
        short8 o;
        o[0] = (short)f2bf(d0 * rstd * g0.x + b0.x);
        o[1] = (short)f2bf(d1 * rstd * g0.y + b0.y);
        o[2] = (short)f2bf(d2 * rstd * g0.z + b0.z);
        o[3] = (short)f2bf(d3 * rstd * g0.w + b0.w);
        o[4] = (short)f2bf(d4 * rstd * g1.x + b1v.x);
        o[5] = (short)f2bf(d5 * rstd * g1.y + b1v.y);
        o[6] = (short)f2bf(d6 * rstd * g1.z + b1v.z);
        o[7] = (short)f2bf(d7 * rstd * g1.w + b1v.w);
        *(short8*)(h2l + r * HCPAD + lane * 8) = o;
    }
    __syncthreads();

    int nb = blockIdx.x * 64 + w * 16;
    short8 af[16];
    #pragma unroll
    for (int ks = 0; ks < 16; ++ks)
        af[ks] = *(const short8*)&h2l[l15 * HCPAD + ks * 32 + quad * 8];

    const ushort* wrow = W1t + (size_t)(nb + l15) * D + quad * 8;
    floatx4 acc = (floatx4)0.f;
    #pragma unroll
    for (int ks = 0; ks < 16; ++ks) {
        short8 bf = *(const short8*)(wrow + ks * 32);
        acc = __builtin_amdgcn_mfma_f32_16x16x32_bf16(af[ks], bf, acc, 0, 0, 0);
    }
    float bv = b1[nb + l15];
    #pragma unroll
    for (int reg = 0; reg < 4; ++reg)
        uc[(size_t)(quad * 4 + reg) * MLPD + nb + l15] = f2bf(fast_gelu(acc[reg] + bv));
}

__global__ __launch_bounds__(256) void gemm2_cls(const ushort* __restrict__ uc,
                                                 const ushort* __restrict__ W2t,
                                                 const float* __restrict__ b2,
                                                 float* __restrict__ p0c) {
    __shared__ float red[4 * 256];
    int tid = threadIdx.x;
    int lane = tid & 63;
    int w = __builtin_amdgcn_readfirstlane(tid >> 6);
    int quad = lane >> 4, l15 = lane & 15;
    int nb = blockIdx.x * 16;

    const ushort* wrow = W2t + (size_t)(nb + l15) * MLPD + quad * 8;
    floatx4 acc = (floatx4)0.f;
    #pragma unroll
    for (int k8 = 0; k8 < 16; ++k8) {
        int ks = w * 16 + k8;
        short8 a2 = *(const short8*)&uc[(size_t)l15 * MLPD + ks * 32 + quad * 8];
        short8 bf = *(const short8*)(wrow + (size_t)ks * 32);
        acc = __builtin_amdgcn_mfma_f32_16x16x32_bf16(a2, bf, acc, 0, 0, 0);
    }
    #pragma unroll
    for (int reg = 0; reg < 4; ++reg)
        red[w * 256 + (quad * 4 + reg) * 16 + l15] = acc[reg];
    __syncthreads();
    int row = tid >> 4, col = tid & 15;
    float s = red[row * 16 + col] + red[256 + row * 16 + col]
            + red[512 + row * 16 + col] + red[768 + row * 16 + col];
    p0c[(size_t)row * D + nb + col] = s + b2[nb + col];
}

// ---------------- head: out[b] = sigmoid((x[b,0]+p0c[b]) . head_W + head_b) ----------------
__global__ void head_kernel(const float* __restrict__ x,
                            const float* __restrict__ p0c,
                            const float* __restrict__ hw,
                            const float* __restrict__ hb,
                            float* __restrict__ out) {
    int b = blockIdx.x;
    int tid = threadIdx.x; // 512
    float s = (x[(size_t)b * T * D + tid] + p0c[(size_t)b * D + tid]) * hw[tid];
    #pragma unroll
    for (int off = 32; off > 0; off >>= 1) s += __shfl_down(s, off, 64);
    __shared__ float red[8];
    if ((tid & 63) == 0) red[tid >> 6] = s;
    __syncthreads();
    if (tid == 0) {
        float t = 0.f;
        #pragma unroll
        for (int i = 0; i < 8; ++i) t += red[i];
        out[b] = 1.0f / (1.0f + __expf(-(t + hb[0])));
    }
}

extern "C" void kernel_launch(void* const* d_in, const int* in_sizes, int n_in,
                              void* d_out, int out_size, void* d_ws, size_t ws_size,
                              hipStream_t stream) {
    const float* src     = (const float*)d_in[0];
    const float* emb_W   = (const float*)d_in[1];
    const float* emb_b   = (const float*)d_in[2];
    const float* cls_tok = (const float*)d_in[3];
    const float* ln1_g   = (const float*)d_in[4];
    const float* ln1_b   = (const float*)d_in[5];
    const float* Wq      = (const float*)d_in[6];
    const float* bq      = (const float*)d_in[7];
    const float* Wk      = (const float*)d_in[8];
    const float* bk      = (const float*)d_in[9];
    const float* Wv      = (const float*)d_in[10];
    const float* bv      = (const float*)d_in[11];
    const float* ln2_g   = (const float*)d_in[12];
    const float* ln2_b   = (const float*)d_in[13];
    const float* W1      = (const float*)d_in[14];
    const float* b1      = (const float*)d_in[15];
    const float* W2      = (const float*)d_in[16];
    const float* b2      = (const float*)d_in[17];
    const float* head_W  = (const float*)d_in[18];
    const float* head_b  = (const float*)d_in[19];

    const size_t NTOK = (size_t)B * T;          // 8192
    char* wsb = (char*)d_ws;
    float*  x    = (float*)wsb;      wsb += NTOK * D * 4;
    ushort* hbuf = (ushort*)wsb;     wsb += NTOK * D * 2;
    ushort* q    = (ushort*)wsb;     wsb += NTOK * D * 2;
    ushort* k    = (ushort*)wsb;     wsb += NTOK * D * 2;
    ushort* vT   = (ushort*)wsb;     wsb += NTOK * D * 2;
    ushort* u    = (ushort*)wsb;     wsb += NTOK * MLPD * 2;
    ushort* W1t  = (ushort*)wsb;     wsb += (size_t)NB * D * MLPD * 2;
    ushort* W2t  = (ushort*)wsb;     wsb += (size_t)NB * D * MLPD * 2;
    ushort* WqT  = (ushort*)wsb;     wsb += (size_t)NB * H * DH * DH * 2;
    ushort* WkT  = (ushort*)wsb;     wsb += (size_t)NB * H * DH * DH * 2;
    ushort* WvT  = (ushort*)wsb;     wsb += (size_t)NB * H * DH * DH * 2;
    ushort* srcb = (ushort*)wsb;     wsb += NTOK * F * 2;
    ushort* embWt= (ushort*)wsb;     wsb += (size_t)F * D * 2;
    ushort* ucls = (ushort*)wsb;     wsb += (size_t)16 * MLPD * 2;
    float*  p0c  = (float*)wsb;      wsb += (size_t)16 * D * 4;

    // weight / input prep (every launch)
    wtrans_kernel<<<dim3(D / 32, MLPD / 32, NB), 256, 0, stream>>>(W1, W1t, D, MLPD);
    wtrans_kernel<<<dim3(MLPD / 32, D / 32, NB), 256, 0, stream>>>(W2, W2t, MLPD, D);
    wtransq_kernel<<<dim3(NB * H, 3), 256, 0, stream>>>(Wq, Wk, Wv, WqT, WkT, WvT);
    wtrans_kernel<<<dim3(F / 32, D / 32, 1), 256, 0, stream>>>(emb_W, embWt, F, D);
    castsrc_kernel<<<B * T * F / 1024, 256, 0, stream>>>(src, srcb);

    embed_gemm<<<dim3(B * T / 64, D / 64), 256, 0, stream>>>(srcb, embWt, emb_b, cls_tok, x);

    for (int i = 0; i < NB; ++i) {
        lnqkv_kernel<<<B * T / 32, 256, 0, stream>>>(x,
            ln1_g + i * D, ln1_b + i * D,
            WqT + (size_t)i * H * DH * DH, bq + (size_t)i * H * DH,
            WkT + (size_t)i * H * DH * DH, bk + (size_t)i * H * DH,
            WvT + (size_t)i * H * DH * DH, bv + (size_t)i * H * DH,
            q, k, vT);
        if (i < NB - 1) {
            attn_kernel<<<dim3(B * H, T / 128), 512, 0, stream>>>(q, k, vT, x);
            ln_kernel<<<B * T / 4, 256, 0, stream>>>(x, ln2_g + i * D, ln2_b + i * D, hbuf);
            gemm1_8p<<<dim3((B * T / 256) * (MLPD / 256)), 512, 0, stream>>>(
                hbuf, W1t + (size_t)i * D * MLPD, b1 + (size_t)i * MLPD, u, MLPD, D);
            gemm_pipe<128, 2><<<dim3(B * T / 128, D / 128), 512, 0, stream>>>(
                u, W2t + (size_t)i * MLPD * D, b2 + (size_t)i * D, x, D, MLPD);
        } else {
            // final layer: only CLS rows matter downstream. Attend only q-tile 0 (rows 0..127),
            // then CLS-only {LN2+MLP-up fused, MLP-down}; head reads x+p0c.
            attn_kernel<<<dim3(B * H, 1), 512, 0, stream>>>(q, k, vT, x);
            lngemm1_cls<<<MLPD / 64, 256, 0, stream>>>(x,
                ln2_g + (size_t)i * D, ln2_b + (size_t)i * D,
                W1t + (size_t)i * D * MLPD, b1 + (size_t)i * MLPD, ucls);
            gemm2_cls<<<D / 16, 256, 0, stream>>>(ucls,
                W2t + (size_t)i * MLPD * D, b2 + (size_t)i * D, p0c);
            head_kernel<<<B, 512, 0, stream>>>(x, p0c, head_W, head_b, (float*)d_out);
        }
    }
}

// Round 12
// 742.722 us; speedup vs baseline: 1.0652x; 1.0082x over previous
//
#include <hip/hip_runtime.h>
#include <hip/hip_bf16.h>
#include <math.h>

#define B 16
#define S 511
#define F 128
#define D 512
#define H 8
#define NB 6
#define DH 64
#define MLPD 2048
#define T 512
#define EPS 1e-5f

typedef unsigned short ushort;
typedef __attribute__((ext_vector_type(8))) short short8;
typedef __attribute__((ext_vector_type(4))) float floatx4;

__device__ __forceinline__ ushort f2bf(float f) {
    union { float f; unsigned u; } cv; cv.f = f;
    unsigned r = (cv.u + 0x7fff + ((cv.u >> 16) & 1)) >> 16;  // RNE
    return (ushort)r;
}

// Branch-free erf (Abramowitz-Stegun 7.1.26, |err| <= 1.5e-7)
__device__ __forceinline__ float fast_gelu(float x) {
    float z = fabsf(x) * 0.70710678118f;
    float t = 1.0f / (1.0f + 0.3275911f * z);
    float p = ((((1.061405429f * t - 1.453152027f) * t + 1.421413741f) * t
               - 0.284496736f) * t + 0.254829592f) * t;
    float erfv = 1.0f - p * __expf(-z * z);
    erfv = copysignf(erfv, x);
    return 0.5f * x * (1.0f + erfv);
}

// ---------------- unified prep: all weight transposes + src cast in ONE dispatch -------------
// blocks 0..6143: W1 [6 x 512x2048] -> W1t      (16x64 32-tiles per mat)
// blocks 6144..12287: W2 [6 x 2048x512] -> W2t  (64x16 tiles per mat)
// blocks 12288..12351: embW [128x512] -> embWt  (4x16 tiles)
// blocks 12352..12495: qkv 48 mats x 3          (one 64x64 mat per block)
// blocks 12496..13519: castsrc (vectorized, 1024 blocks)
__global__ __launch_bounds__(256) void prep_kernel(
        const float* __restrict__ W1, const float* __restrict__ W2,
        const float* __restrict__ embW,
        const float* __restrict__ Wq, const float* __restrict__ Wk,
        const float* __restrict__ Wv,
        const float* __restrict__ src,
        ushort* __restrict__ W1t, ushort* __restrict__ W2t,
        ushort* __restrict__ embWt,
        ushort* __restrict__ WqT, ushort* __restrict__ WkT, ushort* __restrict__ WvT,
        ushort* __restrict__ srcb) {
    __shared__ float tl[64 * 65];    // 16.6 KB; 32x33 path aliases the front
    int idx = blockIdx.x;
    int tid = threadIdx.x;
    if (idx < 12352) {
        const float* W; ushort* Wt; int K, N, kb, nb, mat;
        if (idx < 6144) {
            mat = idx >> 10; int t = idx & 1023;
            kb = (t >> 6) * 32; nb = (t & 63) * 32;
            W = W1; Wt = W1t; K = D; N = MLPD;
        } else if (idx < 12288) {
            int t = idx - 6144; mat = t >> 10; t &= 1023;
            kb = (t >> 4) * 32; nb = (t & 15) * 32;
            W = W2; Wt = W2t; K = MLPD; N = D;
        } else {
            int t = idx - 12288; mat = 0;
            kb = (t >> 4) * 32; nb = (t & 15) * 32;
            W = embW; Wt = embWt; K = F; N = D;
        }
        int c = tid & 31, r0 = tid >> 5;
        const float* Wm = W + (size_t)mat * K * N;
        ushort* Wtm = Wt + (size_t)mat * K * N;
        #pragma unroll
        for (int l = 0; l < 4; ++l) {
            int r = r0 + l * 8;
            tl[r * 33 + c] = Wm[(size_t)(kb + r) * N + nb + c];
        }
        __syncthreads();
        #pragma unroll
        for (int l = 0; l < 4; ++l) {
            int r = r0 + l * 8;
            Wtm[(size_t)(nb + r) * K + kb + c] = f2bf(tl[c * 33 + r]);
        }
    } else if (idx < 12496) {
        int t = idx - 12352;
        int which = t / 48, mat = t - which * 48;
        const float* W = (which == 0 ? Wq : which == 1 ? Wk : Wv) + (size_t)mat * 4096;
        ushort* O = (which == 0 ? WqT : which == 1 ? WkT : WvT) + (size_t)mat * 4096;
        int r0 = tid >> 6, c = tid & 63;
        #pragma unroll
        for (int l = 0; l < 16; ++l) {
            int row = r0 * 16 + l;
            tl[row * 65 + c] = W[row * 64 + c];
        }
        __syncthreads();
        #pragma unroll
        for (int l = 0; l < 16; ++l) {
            int row = r0 * 16 + l;
            O[row * 64 + c] = f2bf(tl[c * 65 + row]);
        }
    } else {
        int t = idx - 12496;
        int gid = t * 256 + tid;                // B*T*F/4 elements total
        int row = gid >> 5;                     // 32 float4-chunks per row (F=128)
        int c4 = (gid & 31) * 4;
        int tt = row & (T - 1), b = row >> 9;
        ushort4 o = {0, 0, 0, 0};
        if (tt > 0) {
            float4 v = *(const float4*)&src[((size_t)b * S + (tt - 1)) * F + c4];
            o.x = f2bf(v.x); o.y = f2bf(v.y); o.z = f2bf(v.z); o.w = f2bf(v.w);
        }
        *(ushort4*)&srcb[(size_t)row * F + c4] = o;
    }
}

// ---------------- async global->LDS helper ----------------
__device__ __forceinline__ void gload_lds16(const ushort* g, ushort* l) {
    __builtin_amdgcn_global_load_lds((const __attribute__((address_space(1))) unsigned int*)g,
                                     (__attribute__((address_space(3))) unsigned int*)l,
                                     16, 0, 0);
}

#define S_WAITCNT_VM(N) asm volatile("s_waitcnt vmcnt(" #N ")" ::: "memory")
#define S_WAITCNT_LGKM0 asm volatile("s_waitcnt lgkmcnt(0)" ::: "memory")
#define S_WAITCNT_LGKM8 asm volatile("s_waitcnt lgkmcnt(8)" ::: "memory")

// ---------------- embed GEMM: x = concat(cls, srcb@embWt^T)+emb_b+pe, fp32 out ----------------
__global__ __launch_bounds__(256) void embed_gemm(const ushort* __restrict__ A,
                                                  const ushort* __restrict__ Bt,
                                                  const float* __restrict__ emb_b,
                                                  const float* __restrict__ cls_tok,
                                                  float* __restrict__ x) {
    __shared__ ushort As[64 * 32];
    __shared__ ushort Bs[64 * 32];
    int tid = threadIdx.x;
    int lane = tid & 63;
    int w = __builtin_amdgcn_readfirstlane(tid >> 6);
    int quad = lane >> 4, l15 = lane & 15;
    int wr = (w >> 1) * 32, wc = (w & 1) * 32;
    int m0 = blockIdx.x * 64, n0 = blockIdx.y * 64;

    floatx4 acc[2][2];
    #pragma unroll
    for (int i = 0; i < 2; ++i)
        #pragma unroll
        for (int j = 0; j < 2; ++j) acc[i][j] = (floatx4)0.f;

    int lrow = lane >> 2;
    int lk = (lane & 3) * 8;
    const ushort* Ag = A + (size_t)(m0 + 16 * w + lrow) * F + lk;
    const ushort* Bg = Bt + (size_t)(n0 + 16 * w + lrow) * F + lk;
    ushort* AsW = &As[16 * w * 32];
    ushort* BsW = &Bs[16 * w * 32];
    int fa = l15 * 32 + quad * 8;

    for (int kt = 0; kt < F; kt += 32) {
        gload_lds16(Ag + kt, AsW);
        gload_lds16(Bg + kt, BsW);
        __syncthreads();
        short8 af[2], bf[2];
        #pragma unroll
        for (int i = 0; i < 2; ++i) af[i] = *(const short8*)&As[(wr + 16 * i) * 32 + fa];
        #pragma unroll
        for (int j = 0; j < 2; ++j) bf[j] = *(const short8*)&Bs[(wc + 16 * j) * 32 + fa];
        #pragma unroll
        for (int i = 0; i < 2; ++i)
            #pragma unroll
            for (int j = 0; j < 2; ++j)
                acc[i][j] = __builtin_amdgcn_mfma_f32_16x16x32_bf16(af[i], bf[j], acc[i][j], 0, 0, 0);
        __syncthreads();
    }

    const float LOG1E4 = 9.210340371976184f;
    int rbase = (lane >> 4) * 4;
    int cidx = lane & 15;
    #pragma unroll
    for (int j = 0; j < 2; ++j) {
        int gc = n0 + wc + 16 * j + cidx;
        float je = (float)(gc & ~1);
        float freq = expf(-(je / (float)D) * LOG1E4);
        float ebv = emb_b[gc];
        float clsv = cls_tok[gc];
        bool odd = (gc & 1);
        #pragma unroll
        for (int i = 0; i < 2; ++i) {
            int gr = m0 + wr + 16 * i + rbase;
            #pragma unroll
            for (int reg = 0; reg < 4; ++reg) {
                int row = gr + reg;
                int t = row & (T - 1);
                float ang = (float)t * freq;
                float pe = odd ? cosf(ang) : sinf(ang);
                float val = (t == 0) ? (clsv + pe) : (acc[i][j][reg] + ebv + pe);
                x[(size_t)row * D + gc] = val;
            }
        }
    }
}

// ---------------- layernorm -> bf16: one wave per row, shuffle-only ----------------
__global__ __launch_bounds__(256) void ln_kernel(const float* __restrict__ xin,
                                                 const float* __restrict__ g,
                                                 const float* __restrict__ bb,
                                                 ushort* __restrict__ out) {
    int lane = threadIdx.x & 63;
    int row = blockIdx.x * 4 + (threadIdx.x >> 6);
    const float* xr = xin + (size_t)row * D + lane * 8;
    float4 a0 = *(const float4*)xr;
    float4 a1 = *(const float4*)(xr + 4);
    float s = a0.x + a0.y + a0.z + a0.w + a1.x + a1.y + a1.z + a1.w;
    #pragma unroll
    for (int off = 1; off < 64; off <<= 1) s += __shfl_xor(s, off);
    float mean = s * (1.0f / (float)D);
    float d0 = a0.x - mean, d1 = a0.y - mean, d2 = a0.z - mean, d3 = a0.w - mean;
    float d4 = a1.x - mean, d5 = a1.y - mean, d6 = a1.z - mean, d7 = a1.w - mean;
    float sq = d0*d0 + d1*d1 + d2*d2 + d3*d3 + d4*d4 + d5*d5 + d6*d6 + d7*d7;
    #pragma unroll
    for (int off = 1; off < 64; off <<= 1) sq += __shfl_xor(sq, off);
    float rstd = rsqrtf(sq * (1.0f / (float)D) + EPS);
    const float* gp = g + lane * 8;
    const float* bp = bb + lane * 8;
    float4 g0 = *(const float4*)gp, g1 = *(const float4*)(gp + 4);
    float4 b0 = *(const float4*)bp, b1 = *(const float4*)(bp + 4);
    short8 o;
    o[0] = (short)f2bf(d0 * rstd * g0.x + b0.x);
    o[1] = (short)f2bf(d1 * rstd * g0.y + b0.y);
    o[2] = (short)f2bf(d2 * rstd * g0.z + b0.z);
    o[3] = (short)f2bf(d3 * rstd * g0.w + b0.w);
    o[4] = (short)f2bf(d4 * rstd * g1.x + b1.x);
    o[5] = (short)f2bf(d5 * rstd * g1.y + b1.y);
    o[6] = (short)f2bf(d6 * rstd * g1.z + b1.z);
    o[7] = (short)f2bf(d7 * rstd * g1.w + b1.w);
    *(short8*)(out + (size_t)row * D + lane * 8) = o;
}

// ---------------- fused LN1 + QKV: 32-row block; LN into padded LDS, then per-head MFMA ------
#define LQPAD 520
__global__ __launch_bounds__(256) void lnqkv_kernel(
        const float* __restrict__ x,
        const float* __restrict__ g, const float* __restrict__ bb,
        const ushort* __restrict__ WqT, const float* __restrict__ bq,
        const ushort* __restrict__ WkT, const float* __restrict__ bk,
        const ushort* __restrict__ WvT, const float* __restrict__ bv,
        ushort* __restrict__ qo, ushort* __restrict__ ko, ushort* __restrict__ vTo) {
    __shared__ ushort hl[32 * LQPAD];   // 33.3 KB
    int tid = threadIdx.x;
    int lane = tid & 63;
    int w = __builtin_amdgcn_readfirstlane(tid >> 6);   // 0..3
    int quad = lane >> 4, l15 = lane & 15;
    int m0 = blockIdx.x * 32;

    for (int it = 0; it < 8; ++it) {
        int lr = it * 4 + w;
        const float* xr = x + (size_t)(m0 + lr) * D + lane * 8;
        float4 a0 = *(const float4*)xr;
        float4 a1 = *(const float4*)(xr + 4);
        float s = a0.x + a0.y + a0.z + a0.w + a1.x + a1.y + a1.z + a1.w;
        #pragma unroll
        for (int off = 1; off < 64; off <<= 1) s += __shfl_xor(s, off);
        float mean = s * (1.0f / (float)D);
        float d0 = a0.x - mean, d1 = a0.y - mean, d2 = a0.z - mean, d3 = a0.w - mean;
        float d4 = a1.x - mean, d5 = a1.y - mean, d6 = a1.z - mean, d7 = a1.w - mean;
        float sq = d0*d0 + d1*d1 + d2*d2 + d3*d3 + d4*d4 + d5*d5 + d6*d6 + d7*d7;
        #pragma unroll
        for (int off = 1; off < 64; off <<= 1) sq += __shfl_xor(sq, off);
        float rstd = rsqrtf(sq * (1.0f / (float)D) + EPS);
        const float* gp = g + lane * 8;
        const float* bp = bb + lane * 8;
        float4 g0 = *(const float4*)gp, g1 = *(const float4*)(gp + 4);
        float4 b0 = *(const float4*)bp, b1v = *(const float4*)(bp + 4);
        short8 o;
        o[0] = (short)f2bf(d0 * rstd * g0.x + b0.x);
        o[1] = (short)f2bf(d1 * rstd * g0.y + b0.y);
        o[2] = (short)f2bf(d2 * rstd * g0.z + b0.z);
        o[3] = (short)f2bf(d3 * rstd * g0.w + b0.w);
        o[4] = (short)f2bf(d4 * rstd * g1.x + b1v.x);
        o[5] = (short)f2bf(d5 * rstd * g1.y + b1v.y);
        o[6] = (short)f2bf(d6 * rstd * g1.z + b1v.z);
        o[7] = (short)f2bf(d7 * rstd * g1.w + b1v.w);
        *(short8*)(hl + lr * LQPAD + lane * 8) = o;
    }
    __syncthreads();

    int bb_ = m0 >> 9;
    #pragma unroll
    for (int hp = 0; hp < 2; ++hp) {
        int hh = w * 2 + hp;
        short8 af[2][2];
        #pragma unroll
        for (int mt = 0; mt < 2; ++mt)
            #pragma unroll
            for (int ks = 0; ks < 2; ++ks)
                af[mt][ks] = *(const short8*)&hl[(mt * 16 + l15) * LQPAD + hh * DH + ks * 32 + quad * 8];

        floatx4 acc[3][2][4];
        #pragma unroll
        for (int xo = 0; xo < 3; ++xo)
            #pragma unroll
            for (int mt = 0; mt < 2; ++mt)
                #pragma unroll
                for (int nt = 0; nt < 4; ++nt) acc[xo][mt][nt] = (floatx4)0.f;

        #pragma unroll
        for (int xo = 0; xo < 3; ++xo) {
            const ushort* WT = (xo == 0 ? WqT : xo == 1 ? WkT : WvT) + (size_t)hh * 4096;
            #pragma unroll
            for (int nt = 0; nt < 4; ++nt) {
                const ushort* wb = WT + (size_t)(nt * 16 + l15) * 64 + quad * 8;
                short8 bf0 = *(const short8*)(wb);
                short8 bf1 = *(const short8*)(wb + 32);
                #pragma unroll
                for (int mt = 0; mt < 2; ++mt) {
                    acc[xo][mt][nt] = __builtin_amdgcn_mfma_f32_16x16x32_bf16(af[mt][0], bf0, acc[xo][mt][nt], 0, 0, 0);
                    acc[xo][mt][nt] = __builtin_amdgcn_mfma_f32_16x16x32_bf16(af[mt][1], bf1, acc[xo][mt][nt], 0, 0, 0);
                }
            }
        }

        int bh = bb_ * H + hh;
        #pragma unroll
        for (int mt = 0; mt < 2; ++mt) {
            int trow = m0 + mt * 16 + quad * 4;
            int tt = trow & (T - 1);
            #pragma unroll
            for (int nt = 0; nt < 4; ++nt) {
                int col = nt * 16 + l15;
                float bqv = bq[hh * DH + col];
                float bkv = bk[hh * DH + col];
                float bvv = bv[hh * DH + col];
                #pragma unroll
                for (int reg = 0; reg < 4; ++reg) {
                    qo[((size_t)bh * T + tt + reg) * DH + col] = f2bf(acc[0][mt][nt][reg] + bqv);
                    ko[((size_t)bh * T + tt + reg) * DH + col] = f2bf(acc[1][mt][nt][reg] + bkv);
                    vTo[((size_t)bh * DH + col) * T + tt + reg] = f2bf(acc[2][mt][nt][reg] + bvv);
                }
            }
        }
    }
}

// ---------------- MFMA flash attention: Q-tile 128 rows, 8 waves (waves 0-3 stage K, 4-7 V) --
#define PSTRIDE 88
__global__ __launch_bounds__(512) void attn_kernel(const ushort* __restrict__ q,
                                                   const ushort* __restrict__ k,
                                                   const ushort* __restrict__ vT,
                                                   float* __restrict__ x) {
    int bh = blockIdx.x;
    int qt = blockIdx.y;                                // 0..T/128-1
    int b = bh >> 3, hh = bh & 7;
    int tid = threadIdx.x;
    int lane = tid & 63;
    int w = __builtin_amdgcn_readfirstlane(tid >> 6);   // 0..7
    int quad = lane >> 4, l15 = lane & 15;

    __shared__ __align__(16) ushort smem[27648];        // K dbuf 16KB | V dbuf 16KB | P 8x2816B
    ushort* Pw = smem + 16384 + w * (16 * PSTRIDE);

    const ushort* qbase = q + ((size_t)bh * T + qt * 128 + w * 16 + l15) * DH + quad * 8;
    short8 Qf0 = *(const short8*)(qbase);
    short8 Qf1 = *(const short8*)(qbase + 32);

    const ushort* kbase = k + (size_t)bh * T * DH;
    const ushort* vbase = vT + (size_t)bh * DH * T;

    int srow = lane >> 2;
    int scol = (lane & 3) * 8;
    int wk = w & 3;
    bool isK = (w < 4);
    const ushort* sg = isK ? (kbase + (size_t)(wk * 16 + srow) * DH + scol)
                           : (vbase + (size_t)(wk * 16 + srow) * T + scol);
    int sstep = isK ? (64 * DH) : 64;
    ushort* ldsS = smem + (isK ? 0 : 8192) + wk * 16 * 32;

    float l_i[4] = {0.f, 0.f, 0.f, 0.f};
    floatx4 O[4];
    #pragma unroll
    for (int j = 0; j < 4; ++j) O[j] = (floatx4)0.f;

    gload_lds16(sg, ldsS);
    gload_lds16(sg + 32, ldsS + 2048);
    __syncthreads();

    for (int kt = 0; kt < T / 64; ++kt) {
        int cur = kt & 1;
        if (kt < T / 64 - 1) {
            int nb = cur ^ 1;
            const ushort* sgn = sg + (size_t)(kt + 1) * sstep;
            gload_lds16(sgn, ldsS + nb * 4096);
            gload_lds16(sgn + 32, ldsS + nb * 4096 + 2048);
        }
        const ushort* Kc = smem + cur * 4096;
        const ushort* Vc = smem + 8192 + cur * 4096;

        floatx4 sc[4];
        __builtin_amdgcn_s_setprio(1);
        #pragma unroll
        for (int j = 0; j < 4; ++j) {
            int ro = (j * 16 + l15) * 32 + quad * 8;
            short8 kf0 = *(const short8*)&Kc[ro];
            short8 kf1 = *(const short8*)&Kc[2048 + ro];
            floatx4 s4 = (floatx4)0.f;
            s4 = __builtin_amdgcn_mfma_f32_16x16x32_bf16(Qf0, kf0, s4, 0, 0, 0);
            s4 = __builtin_amdgcn_mfma_f32_16x16x32_bf16(Qf1, kf1, s4, 0, 0, 0);
            sc[j] = s4;
        }
        __builtin_amdgcn_s_setprio(0);
        #pragma unroll
        for (int j = 0; j < 4; ++j) {
            #pragma unroll
            for (int r = 0; r < 4; ++r) {
                float p = __expf(sc[j][r] * 0.125f);
                l_i[r] += p;
                Pw[(quad * 4 + r) * PSTRIDE + j * 16 + l15] = f2bf(p);
            }
        }

        short8 af0 = *(const short8*)&Pw[l15 * PSTRIDE + quad * 8];
        short8 af1 = *(const short8*)&Pw[l15 * PSTRIDE + 32 + quad * 8];
        __builtin_amdgcn_s_setprio(1);
        #pragma unroll
        for (int j = 0; j < 4; ++j) {
            int ro = (j * 16 + l15) * 32 + quad * 8;
            short8 vf0 = *(const short8*)&Vc[ro];
            short8 vf1 = *(const short8*)&Vc[2048 + ro];
            O[j] = __builtin_amdgcn_mfma_f32_16x16x32_bf16(af0, vf0, O[j], 0, 0, 0);
            O[j] = __builtin_amdgcn_mfma_f32_16x16x32_bf16(af1, vf1, O[j], 0, 0, 0);
        }
        __builtin_amdgcn_s_setprio(0);
        __syncthreads();
    }

    #pragma unroll
    for (int r = 0; r < 4; ++r) {
        l_i[r] += __shfl_xor(l_i[r], 1);
        l_i[r] += __shfl_xor(l_i[r], 2);
        l_i[r] += __shfl_xor(l_i[r], 4);
        l_i[r] += __shfl_xor(l_i[r], 8);
    }

    float* Ow = (float*)smem + w * 16 * 68;
    #pragma unroll
    for (int r = 0; r < 4; ++r) {
        float rl = 1.0f / l_i[r];
        #pragma unroll
        for (int j = 0; j < 4; ++j)
            Ow[(quad * 4 + r) * 68 + j * 16 + l15] = O[j][r] * rl;
    }
    __syncthreads();
    int r4 = lane >> 4;
    int c16 = lane & 15;
    #pragma unroll
    for (int i = 0; i < 4; ++i) {
        int lrow = i * 4 + r4;
        float4 o = *(const float4*)&Ow[lrow * 68 + c16 * 4];
        int grow = qt * 128 + w * 16 + lrow;
        float* xp = &x[((size_t)(b * T) + grow) * D + hh * DH + c16 * 4];
        float4 xv = *(const float4*)xp;
        xv.x += o.x; xv.y += o.y; xv.z += o.z; xv.w += o.w;
        *(float4*)xp = xv;
    }
}

// ---------------- gemm1: m201-style 256x256 8-phase, BK=64, 2 K-tiles/iter, counted vmcnt ----
__global__ __launch_bounds__(512, 1) void gemm1_8p(const ushort* __restrict__ A,
                                                   const ushort* __restrict__ Bt,
                                                   const float* __restrict__ bias,
                                                   ushort* __restrict__ C,
                                                   int N, int K) {
    constexpr int BUF = 32768;
    constexpr int BOFS = 16384;
    __shared__ ushort lds[2 * BUF];

    int tid = threadIdx.x;
    int lane = tid & 63;
    int w = __builtin_amdgcn_readfirstlane(tid >> 6);
    int quad = lane >> 4, l15 = lane & 15;
    int wm = w >> 2, wn = w & 3;
    int wmr = wm * 128, wnr = wn * 64;

    int nwg = gridDim.x;
    int id = blockIdx.x;
    int idx = (id & 7) * (nwg >> 3) + (id >> 3);
    int NTg = N >> 8;
    int mt = idx / NTg, nt = idx - mt * NTg;
    int m0 = mt * 256, n0 = nt * 256;

    int strow = tid >> 3;
    int ssw = ((tid & 7) ^ (strow & 7)) * 8;
    const ushort* Ag = A + (size_t)(m0 + strow) * K + ssw;
    const ushort* Bg = Bt + (size_t)(n0 + strow) * K + ssw;
    int wdst = w << 9;

    int sx0 = (quad ^ (l15 & 7)) * 8;
    int sx1 = ((4 + quad) ^ (l15 & 7)) * 8;

    floatx4 acc[8][4];
    #pragma unroll
    for (int i = 0; i < 8; ++i)
        #pragma unroll
        for (int n = 0; n < 4; ++n) acc[i][n] = (floatx4)0.f;

    short8 a[4][2], b[4][2];

    #define STG_AH(h, t, bp) do {                                                         \
        gload_lds16(Ag + (size_t)((h) * 128) * K + (size_t)(t) * 64,                      \
                    (bp) + ((h) * 128) * 64 + wdst);                                      \
        gload_lds16(Ag + (size_t)((h) * 128 + 64) * K + (size_t)(t) * 64,                 \
                    (bp) + ((h) * 128 + 64) * 64 + wdst);                                 \
    } while (0)
    #define STG_BH(h, t, bp) do {                                                         \
        gload_lds16(Bg + (size_t)((h) * 128) * K + (size_t)(t) * 64,                      \
                    (bp) + BOFS + ((h) * 128) * 64 + wdst);                                \
        gload_lds16(Bg + (size_t)((h) * 128 + 64) * K + (size_t)(t) * 64,                 \
                    (bp) + BOFS + ((h) * 128 + 64) * 64 + wdst);                           \
    } while (0)

    #define RD_A03(bp) do { _Pragma("unroll")                                             \
        for (int ks = 0; ks < 2; ++ks) { int sx = ks ? sx1 : sx0;                         \
            _Pragma("unroll")                                                             \
            for (int i = 0; i < 4; ++i)                                                   \
                a[i][ks] = *(const short8*)&(bp)[(wmr + i * 16 + l15) * 64 + sx]; } } while (0)
    #define RD_A47(bp) do { _Pragma("unroll")                                             \
        for (int ks = 0; ks < 2; ++ks) { int sx = ks ? sx1 : sx0;                         \
            _Pragma("unroll")                                                             \
            for (int i = 0; i < 4; ++i)                                                   \
                a[i][ks] = *(const short8*)&(bp)[(wmr + (4 + i) * 16 + l15) * 64 + sx]; } } while (0)
    #define RD_B01(bp) do { _Pragma("unroll")                                             \
        for (int ks = 0; ks < 2; ++ks) { int sx = ks ? sx1 : sx0;                         \
            _Pragma("unroll")                                                             \
            for (int n = 0; n < 2; ++n)                                                   \
                b[n][ks] = *(const short8*)&(bp)[BOFS + (wnr + n * 16 + l15) * 64 + sx]; } } while (0)
    #define RD_B23(bp) do { _Pragma("unroll")                                             \
        for (int ks = 0; ks < 2; ++ks) { int sx = ks ? sx1 : sx0;                         \
            _Pragma("unroll")                                                             \
            for (int n = 0; n < 2; ++n)                                                   \
                b[2 + n][ks] = *(const short8*)&(bp)[BOFS + (wnr + (2 + n) * 16 + l15) * 64 + sx]; } } while (0)

    #define MFQ(mb, nb2) do { _Pragma("unroll")                                           \
        for (int ks = 0; ks < 2; ++ks)                                                    \
            _Pragma("unroll")                                                             \
            for (int i = 0; i < 4; ++i)                                                   \
                _Pragma("unroll")                                                         \
                for (int n = 0; n < 2; ++n)                                               \
                    acc[(mb) + i][(nb2) + n] = __builtin_amdgcn_mfma_f32_16x16x32_bf16(   \
                        a[i][ks], b[(nb2) + n][ks], acc[(mb) + i][(nb2) + n], 0, 0, 0); } while (0)

    #define BAR __builtin_amdgcn_s_barrier()
    #define PRIO_MFQ(mb, nb2) do { __builtin_amdgcn_s_setprio(1); MFQ(mb, nb2);           \
                                   __builtin_amdgcn_s_setprio(0); } while (0)

    ushort* buf0 = lds;
    ushort* buf1 = lds + BUF;

    STG_AH(0, 0, buf0); STG_AH(1, 0, buf0); STG_BH(0, 0, buf0); STG_BH(1, 0, buf0);
    STG_BH(0, 1, buf1); STG_BH(1, 1, buf1); STG_AH(0, 1, buf1);
    S_WAITCNT_VM(6);
    BAR;

    int NITER = K >> 7;
    int NT = K >> 6;
    for (int it = 0; it < NITER; ++it) {
        int t2 = 2 * it + 2, t3 = 2 * it + 3;
        bool s2 = (t2 < NT);
        RD_A03(buf0); RD_B01(buf0);
        STG_AH(1, 2 * it + 1, buf1);
        S_WAITCNT_LGKM8;
        BAR; S_WAITCNT_LGKM0; PRIO_MFQ(0, 0); BAR;
        RD_B23(buf0);
        BAR; S_WAITCNT_LGKM0; PRIO_MFQ(0, 2); BAR;
        RD_A47(buf0);
        if (s2) { STG_BH(0, t2, buf0); STG_BH(1, t2, buf0); }
        BAR; S_WAITCNT_LGKM0; PRIO_MFQ(4, 2); BAR;
        if (s2) { STG_AH(0, t2, buf0); S_WAITCNT_VM(6); } else { S_WAITCNT_VM(0); }
        BAR; PRIO_MFQ(4, 0); BAR;
        RD_A03(buf1); RD_B01(buf1);
        if (s2) STG_AH(1, t2, buf0);
        S_WAITCNT_LGKM8;
        BAR; S_WAITCNT_LGKM0; PRIO_MFQ(0, 0); BAR;
        RD_B23(buf1);
        BAR; S_WAITCNT_LGKM0; PRIO_MFQ(0, 2); BAR;
        RD_A47(buf1);
        if (s2) { STG_BH(0, t3, buf1); STG_BH(1, t3, buf1); }
        BAR; S_WAITCNT_LGKM0; PRIO_MFQ(4, 2); BAR;
        if (s2) { STG_AH(0, t3, buf1); S_WAITCNT_VM(6); }
        BAR; PRIO_MFQ(4, 0); BAR;
    }

    #undef STG_AH
    #undef STG_BH
    #undef RD_A03
    #undef RD_A47
    #undef RD_B01
    #undef RD_B23
    #undef MFQ
    #undef BAR
    #undef PRIO_MFQ

    int rbase = quad * 4;
    #pragma unroll
    for (int i = 0; i < 8; ++i) {
        #pragma unroll
        for (int n = 0; n < 4; ++n) {
            int gc = n0 + wnr + n * 16 + l15;
            float bv = bias[gc];
            int gr = m0 + wmr + i * 16 + rbase;
            #pragma unroll
            for (int reg = 0; reg < 4; ++reg) {
                C[(size_t)(gr + reg) * N + gc] = f2bf(fast_gelu(acc[i][n][reg] + bv));
            }
        }
    }
}

// ---------------- pipelined MFMA GEMM (gemm2, r1 bench-best): 3-buffer LDS, distance 2 ------
template<int BM, int EPI>
__global__ __launch_bounds__(512) void gemm_pipe(const ushort* __restrict__ A,
                                                 const ushort* __restrict__ Bt,
                                                 const float* __restrict__ bias,
                                                 void* __restrict__ Cout,
                                                 int N, int K) {
    constexpr int BN = 128;
    constexpr int BK = 64;
    constexpr int MREP = BM / 32;
    constexpr int AJ = BM / 64;
    constexpr int TILE = (BM + BN) * BK;
    __shared__ ushort lds[3 * TILE];

    int tid = threadIdx.x;
    int lane = tid & 63;
    int w = __builtin_amdgcn_readfirstlane(tid >> 6);
    int quad = lane >> 4, l15 = lane & 15;
    int wrow = (w >> 2) * (BM / 2);
    int wcol = (w & 3) * 32;
    int m0 = blockIdx.x * BM, n0 = blockIdx.y * BN;

    int lrow8 = lane >> 3;
    int lslot = lane & 7;
    int scol = (lslot ^ lrow8) * 8;
    const ushort* Asrc = A + (size_t)(m0 + w * 8 + lrow8) * K + scol;
    const ushort* Bsrc = Bt + (size_t)(n0 + w * 8 + lrow8) * K + scol;
    ushort* ldsA0 = lds + (w * 8) * BK;
    ushort* ldsB0 = lds + BM * BK + (w * 8) * BK;

    int sx0 = ((quad) ^ (l15 & 7)) * 8;
    int sx1 = ((4 + quad) ^ (l15 & 7)) * 8;

    floatx4 acc[MREP][2];
    #pragma unroll
    for (int i = 0; i < MREP; ++i) {
        acc[i][0] = (floatx4)0.f;
        acc[i][1] = (floatx4)0.f;
    }

    #define STAGE_T(t, buf) do {                                                   \
        const ushort* ap_ = Asrc + (size_t)(t) * BK;                               \
        const ushort* bp_ = Bsrc + (size_t)(t) * BK;                               \
        ushort* la_ = ldsA0 + (buf) * TILE;                                        \
        ushort* lb_ = ldsB0 + (buf) * TILE;                                        \
        _Pragma("unroll")                                                          \
        for (int j = 0; j < AJ; ++j)                                               \
            gload_lds16(ap_ + (size_t)j * 64 * K, la_ + j * 64 * BK);              \
        _Pragma("unroll")                                                          \
        for (int j = 0; j < 2; ++j)                                                \
            gload_lds16(bp_ + (size_t)j * 64 * K, lb_ + j * 64 * BK);              \
    } while (0)

    #define COMPUTE_T(buf) do {                                                    \
        const ushort* Ab_ = lds + (buf) * TILE;                                    \
        const ushort* Bb_ = Ab_ + BM * BK;                                         \
        _Pragma("unroll")                                                          \
        for (int ks = 0; ks < 2; ++ks) {                                           \
            int sx_ = ks ? sx1 : sx0;                                              \
            short8 bfr0 = *(const short8*)&Bb_[(wcol + l15) * BK + sx_];           \
            short8 bfr1 = *(const short8*)&Bb_[(wcol + 16 + l15) * BK + sx_];      \
            _Pragma("unroll")                                                      \
            for (int i = 0; i < MREP; ++i) {                                       \
                short8 af_ = *(const short8*)&Ab_[(wrow + i * 16 + l15) * BK + sx_]; \
                acc[i][0] = __builtin_amdgcn_mfma_f32_16x16x32_bf16(af_, bfr0, acc[i][0], 0, 0, 0); \
                acc[i][1] = __builtin_amdgcn_mfma_f32_16x16x32_bf16(af_, bfr1, acc[i][1], 0, 0, 0); \
            }                                                                      \
        }                                                                          \
    } while (0)

    STAGE_T(0, 0);
    STAGE_T(1, 1);

    int NT = K / BK;
    int cb = 0, nbuf = 2;
    for (int t = 0; t < NT - 2; ++t) {
        STAGE_T(t + 2, nbuf);
        if constexpr (AJ == 4) { S_WAITCNT_VM(12); } else { S_WAITCNT_VM(8); }
        __builtin_amdgcn_s_barrier();
        __builtin_amdgcn_s_setprio(1);
        COMPUTE_T(cb);
        __builtin_amdgcn_s_setprio(0);
        asm volatile("s_waitcnt lgkmcnt(0)" ::: "memory");
        __builtin_amdgcn_s_barrier();
        cb = (cb == 2) ? 0 : cb + 1;
        nbuf = (nbuf == 2) ? 0 : nbuf + 1;
    }
    if constexpr (AJ == 4) { S_WAITCNT_VM(6); } else { S_WAITCNT_VM(4); }
    __builtin_amdgcn_s_barrier();
    __builtin_amdgcn_s_setprio(1);
    COMPUTE_T(cb);
    __builtin_amdgcn_s_setprio(0);
    asm volatile("s_waitcnt lgkmcnt(0)" ::: "memory");
    __builtin_amdgcn_s_barrier();
    cb = (cb == 2) ? 0 : cb + 1;
    S_WAITCNT_VM(0);
    __builtin_amdgcn_s_barrier();
    COMPUTE_T(cb);

    #undef STAGE_T
    #undef COMPUTE_T

    int rbase = quad * 4;
    #pragma unroll
    for (int i = 0; i < MREP; ++i) {
        #pragma unroll
        for (int n = 0; n < 2; ++n) {
            int gc = n0 + wcol + n * 16 + l15;
            float bv = bias[gc];
            int gr = m0 + wrow + i * 16 + rbase;
            #pragma unroll
            for (int reg = 0; reg < 4; ++reg) {
                if constexpr (EPI == 0) {
                    ((ushort*)Cout)[(size_t)(gr + reg) * N + gc] =
                        f2bf(fast_gelu(acc[i][n][reg] + bv));
                } else if constexpr (EPI == 1) {
                    ((float*)Cout)[(size_t)(gr + reg) * N + gc] = acc[i][n][reg] + bv;
                } else {
                    float* xp = (float*)Cout + (size_t)(gr + reg) * N + gc;
                    *xp = *xp + acc[i][n][reg] + bv;
                }
            }
        }
    }
}

// ---------------- CLS-only final layer: fused LN + MLP-up (per-block redundant LN) ----------
#define HCPAD 520
__global__ __launch_bounds__(256) void lngemm1_cls(const float* __restrict__ x,
                                                   const float* __restrict__ g,
                                                   const float* __restrict__ bb,
                                                   const ushort* __restrict__ W1t,
                                                   const float* __restrict__ b1,
                                                   ushort* __restrict__ uc) {
    __shared__ ushort h2l[16 * HCPAD];   // 16.6 KB
    int tid = threadIdx.x;
    int lane = tid & 63;
    int w = __builtin_amdgcn_readfirstlane(tid >> 6);   // 0..3
    int quad = lane >> 4, l15 = lane & 15;

    #pragma unroll
    for (int it = 0; it < 4; ++it) {
        int r = it * 4 + w;
        const float* xr = x + (size_t)r * T * D + lane * 8;
        float4 a0 = *(const float4*)xr;
        float4 a1 = *(const float4*)(xr + 4);
        float s = a0.x + a0.y + a0.z + a0.w + a1.x + a1.y + a1.z + a1.w;
        #pragma unroll
        for (int off = 1; off < 64; off <<= 1) s += __shfl_xor(s, off);
        float mean = s * (1.0f / (float)D);
        float d0 = a0.x - mean, d1 = a0.y - mean, d2 = a0.z - mean, d3 = a0.w - mean;
        float d4 = a1.x - mean, d5 = a1.y - mean, d6 = a1.z - mean, d7 = a1.w - mean;
        float sq = d0*d0 + d1*d1 + d2*d2 + d3*d3 + d4*d4 + d5*d5 + d6*d6 + d7*d7;
        #pragma unroll
        for (int off = 1; off < 64; off <<= 1) sq += __shfl_xor(sq, off);
        float rstd = rsqrtf(sq * (1.0f / (float)D) + EPS);
        const float* gp = g + lane * 8;
        const float* bp = bb + lane * 8;
        float4 g0 = *(const float4*)gp, g1 = *(const float4*)(gp + 4);
        float4 b0 = *(const float4*)bp, b1v = *(const float4*)(bp + 4);
        short8 o;
        o[0] = (short)f2bf(d0 * rstd * g0.x + b0.x);
        o[1] = (short)f2bf(d1 * rstd * g0.y + b0.y);
        o[2] = (short)f2bf(d2 * rstd * g0.z + b0.z);
        o[3] = (short)f2bf(d3 * rstd * g0.w + b0.w);
        o[4] = (short)f2bf(d4 * rstd * g1.x + b1v.x);
        o[5] = (short)f2bf(d5 * rstd * g1.y + b1v.y);
        o[6] = (short)f2bf(d6 * rstd * g1.z + b1v.z);
        o[7] = (short)f2bf(d7 * rstd * g1.w + b1v.w);
        *(short8*)(h2l + r * HCPAD + lane * 8) = o;
    }
    __syncthreads();

    int nb = blockIdx.x * 64 + w * 16;
    short8 af[16];
    #pragma unroll
    for (int ks = 0; ks < 16; ++ks)
        af[ks] = *(const short8*)&h2l[l15 * HCPAD + ks * 32 + quad * 8];

    const ushort* wrow = W1t + (size_t)(nb + l15) * D + quad * 8;
    floatx4 acc = (floatx4)0.f;
    #pragma unroll
    for (int ks = 0; ks < 16; ++ks) {
        short8 bf = *(const short8*)(wrow + ks * 32);
        acc = __builtin_amdgcn_mfma_f32_16x16x32_bf16(af[ks], bf, acc, 0, 0, 0);
    }
    float bv = b1[nb + l15];
    #pragma unroll
    for (int reg = 0; reg < 4; ++reg)
        uc[(size_t)(quad * 4 + reg) * MLPD + nb + l15] = f2bf(fast_gelu(acc[reg] + bv));
}

__global__ __launch_bounds__(256) void gemm2_cls(const ushort* __restrict__ uc,
                                                 const ushort* __restrict__ W2t,
                                                 const float* __restrict__ b2,
                                                 float* __restrict__ p0c) {
    __shared__ float red[4 * 256];
    int tid = threadIdx.x;
    int lane = tid & 63;
    int w = __builtin_amdgcn_readfirstlane(tid >> 6);
    int quad = lane >> 4, l15 = lane & 15;
    int nb = blockIdx.x * 16;

    const ushort* wrow = W2t + (size_t)(nb + l15) * MLPD + quad * 8;
    floatx4 acc = (floatx4)0.f;
    #pragma unroll
    for (int k8 = 0; k8 < 16; ++k8) {
        int ks = w * 16 + k8;
        short8 a2 = *(const short8*)&uc[(size_t)l15 * MLPD + ks * 32 + quad * 8];
        short8 bf = *(const short8*)(wrow + (size_t)ks * 32);
        acc = __builtin_amdgcn_mfma_f32_16x16x32_bf16(a2, bf, acc, 0, 0, 0);
    }
    #pragma unroll
    for (int reg = 0; reg < 4; ++reg)
        red[w * 256 + (quad * 4 + reg) * 16 + l15] = acc[reg];
    __syncthreads();
    int row = tid >> 4, col = tid & 15;
    float s = red[row * 16 + col] + red[256 + row * 16 + col]
            + red[512 + row * 16 + col] + red[768 + row * 16 + col];
    p0c[(size_t)row * D + nb + col] = s + b2[nb + col];
}

// ---------------- head: out[b] = sigmoid((x[b,0]+p0c[b]) . head_W + head_b) ----------------
__global__ void head_kernel(const float* __restrict__ x,
                            const float* __restrict__ p0c,
                            const float* __restrict__ hw,
                            const float* __restrict__ hb,
                            float* __restrict__ out) {
    int b = blockIdx.x;
    int tid = threadIdx.x; // 512
    float s = (x[(size_t)b * T * D + tid] + p0c[(size_t)b * D + tid]) * hw[tid];
    #pragma unroll
    for (int off = 32; off > 0; off >>= 1) s += __shfl_down(s, off, 64);
    __shared__ float red[8];
    if ((tid & 63) == 0) red[tid >> 6] = s;
    __syncthreads();
    if (tid == 0) {
        float t = 0.f;
        #pragma unroll
        for (int i = 0; i < 8; ++i) t += red[i];
        out[b] = 1.0f / (1.0f + __expf(-(t + hb[0])));
    }
}

extern "C" void kernel_launch(void* const* d_in, const int* in_sizes, int n_in,
                              void* d_out, int out_size, void* d_ws, size_t ws_size,
                              hipStream_t stream) {
    const float* src     = (const float*)d_in[0];
    const float* emb_W   = (const float*)d_in[1];
    const float* emb_b   = (const float*)d_in[2];
    const float* cls_tok = (const float*)d_in[3];
    const float* ln1_g   = (const float*)d_in[4];
    const float* ln1_b   = (const float*)d_in[5];
    const float* Wq      = (const float*)d_in[6];
    const float* bq      = (const float*)d_in[7];
    const float* Wk      = (const float*)d_in[8];
    const float* bk      = (const float*)d_in[9];
    const float* Wv      = (const float*)d_in[10];
    const float* bv      = (const float*)d_in[11];
    const float* ln2_g   = (const float*)d_in[12];
    const float* ln2_b   = (const float*)d_in[13];
    const float* W1      = (const float*)d_in[14];
    const float* b1      = (const float*)d_in[15];
    const float* W2      = (const float*)d_in[16];
    const float* b2      = (const float*)d_in[17];
    const float* head_W  = (const float*)d_in[18];
    const float* head_b  = (const float*)d_in[19];

    const size_t NTOK = (size_t)B * T;          // 8192
    char* wsb = (char*)d_ws;
    float*  x    = (float*)wsb;      wsb += NTOK * D * 4;
    ushort* hbuf = (ushort*)wsb;     wsb += NTOK * D * 2;
    ushort* q    = (ushort*)wsb;     wsb += NTOK * D * 2;
    ushort* k    = (ushort*)wsb;     wsb += NTOK * D * 2;
    ushort* vT   = (ushort*)wsb;     wsb += NTOK * D * 2;
    ushort* u    = (ushort*)wsb;     wsb += NTOK * MLPD * 2;
    ushort* W1t  = (ushort*)wsb;     wsb += (size_t)NB * D * MLPD * 2;
    ushort* W2t  = (ushort*)wsb;     wsb += (size_t)NB * D * MLPD * 2;
    ushort* WqT  = (ushort*)wsb;     wsb += (size_t)NB * H * DH * DH * 2;
    ushort* WkT  = (ushort*)wsb;     wsb += (size_t)NB * H * DH * DH * 2;
    ushort* WvT  = (ushort*)wsb;     wsb += (size_t)NB * H * DH * DH * 2;
    ushort* srcb = (ushort*)wsb;     wsb += NTOK * F * 2;
    ushort* embWt= (ushort*)wsb;     wsb += (size_t)F * D * 2;
    ushort* ucls = (ushort*)wsb;     wsb += (size_t)16 * MLPD * 2;
    float*  p0c  = (float*)wsb;      wsb += (size_t)16 * D * 4;

    // unified weight/input prep: 1 dispatch (was 5)
    prep_kernel<<<13520, 256, 0, stream>>>(W1, W2, emb_W, Wq, Wk, Wv, src,
                                           W1t, W2t, embWt, WqT, WkT, WvT, srcb);

    embed_gemm<<<dim3(B * T / 64, D / 64), 256, 0, stream>>>(srcb, embWt, emb_b, cls_tok, x);

    for (int i = 0; i < NB; ++i) {
        lnqkv_kernel<<<B * T / 32, 256, 0, stream>>>(x,
            ln1_g + i * D, ln1_b + i * D,
            WqT + (size_t)i * H * DH * DH, bq + (size_t)i * H * DH,
            WkT + (size_t)i * H * DH * DH, bk + (size_t)i * H * DH,
            WvT + (size_t)i * H * DH * DH, bv + (size_t)i * H * DH,
            q, k, vT);
        if (i < NB - 1) {
            attn_kernel<<<dim3(B * H, T / 128), 512, 0, stream>>>(q, k, vT, x);
            ln_kernel<<<B * T / 4, 256, 0, stream>>>(x, ln2_g + i * D, ln2_b + i * D, hbuf);
            gemm1_8p<<<dim3((B * T / 256) * (MLPD / 256)), 512, 0, stream>>>(
                hbuf, W1t + (size_t)i * D * MLPD, b1 + (size_t)i * MLPD, u, MLPD, D);
            gemm_pipe<128, 2><<<dim3(B * T / 128, D / 128), 512, 0, stream>>>(
                u, W2t + (size_t)i * MLPD * D, b2 + (size_t)i * D, x, D, MLPD);
        } else {
            // final layer: only CLS rows matter downstream. Attend only q-tile 0 (rows 0..127),
            // then CLS-only {LN2+MLP-up fused, MLP-down}; head reads x+p0c.
            attn_kernel<<<dim3(B * H, 1), 512, 0, stream>>>(q, k, vT, x);
            lngemm1_cls<<<MLPD / 64, 256, 0, stream>>>(x,
                ln2_g + (size_t)i * D, ln2_b + (size_t)i * D,
                W1t + (size_t)i * D * MLPD, b1 + (size_t)i * MLPD, ucls);
            gemm2_cls<<<D / 16, 256, 0, stream>>>(ucls,
                W2t + (size_t)i * MLPD * D, b2 + (size_t)i * D, p0c);
            head_kernel<<<B, 512, 0, stream>>>(x, p0c, head_W, head_b, (float*)d_out);
        }
    }
}